// Round 4
// baseline (669.209 us; speedup 1.0000x reference)
//
#include <hip/hip_runtime.h>
#include <cstddef>

#define D 256
#define H 8
#define HD 32
#define ED 64
#define EB 16

typedef __attribute__((ext_vector_type(8))) short short8;
typedef __attribute__((ext_vector_type(4))) short short4v;
typedef __attribute__((ext_vector_type(4))) float floatx4;

// fp32 -> bf16 RNE
__device__ inline short f2bf(float f) {
    unsigned u = __float_as_uint(f);
    unsigned r = (u + 0x7fffu + ((u >> 16) & 1u)) >> 16;
    return (short)r;
}

// ---------------- activations ----------------
template<int ACT> __device__ inline float act_f(float v) {
    if (ACT == 1) return fmaxf(v, 0.f);
    if (ACT == 2) return v > 0.f ? v : expm1f(v);              // elu
    if (ACT == 3) return 0.5f * v * (1.f + erff(v * 0.70710678118654752f)); // exact gelu
    return v;
}

__device__ inline float wave_sum(float v) {
#pragma unroll
    for (int off = 32; off > 0; off >>= 1) v += __shfl_xor(v, off, 64);
    return v;
}

// ================= edge binning pipeline =================
__global__ void zero_kernel(int* __restrict__ p, int n) {
    int i = blockIdx.x * 256 + threadIdx.x;
    if (i < n) p[i] = 0;
}

__global__ void hist_kernel(const int* __restrict__ ei, int* __restrict__ cnt, int E) {
    int e = blockIdx.x * 256 + threadIdx.x;
    if (e < E) atomicAdd(&cnt[ei[E + e]], 1);
}

// single block, 1024 threads, N=4096 counters -> exclusive offsets.
// cnt is rewritten in-place with the exclusive starts (scatter cursor).
__global__ __launch_bounds__(1024) void scan_kernel(int* __restrict__ cnt,
                                                    int* __restrict__ offs) {
    __shared__ int s[1024];
    int tid = threadIdx.x;
    int4 c = *(int4*)&cnt[tid * 4];
    int sum = c.x + c.y + c.z + c.w;
    s[tid] = sum;
    __syncthreads();
    for (int off = 1; off < 1024; off <<= 1) {
        int v = (tid >= off) ? s[tid - off] : 0;
        __syncthreads();
        s[tid] += v;
        __syncthreads();
    }
    int ex = s[tid] - sum;
    int o1 = ex + c.x, o2 = o1 + c.y, o3 = o2 + c.z;
    offs[tid * 4] = ex; offs[tid * 4 + 1] = o1;
    offs[tid * 4 + 2] = o2; offs[tid * 4 + 3] = o3;
    cnt[tid * 4] = ex; cnt[tid * 4 + 1] = o1;
    cnt[tid * 4 + 2] = o2; cnt[tid * 4 + 3] = o3;
    if (tid == 1023) offs[4096] = s[1023];
}

__global__ void scatter_kernel(const int* __restrict__ ei, int* __restrict__ cursor,
                               int* __restrict__ perm, int E) {
    int e = blockIdx.x * 256 + threadIdx.x;
    if (e < E) {
        int pos = atomicAdd(&cursor[ei[E + e]], 1);
        perm[pos] = e;
    }
}

// one block per dst node: h[node] = (1+eps)*x[node] + sum relu(x[src]+ea@Wl+bl)
__global__ __launch_bounds__(256) void agg_kernel(
        const float* __restrict__ x, const int* __restrict__ ei,
        const float* __restrict__ ea, const float* __restrict__ Wl,
        const float* __restrict__ bl, const float* __restrict__ eps,
        const int* __restrict__ offs, const int* __restrict__ perm,
        float* __restrict__ h, int E) {
    __shared__ float s_ea[EB][ED];
    __shared__ int s_src[EB], s_eid[EB];
    int node = blockIdx.x, tid = threadIdx.x;
    float w[ED];
#pragma unroll
    for (int k = 0; k < ED; k++) w[k] = Wl[k * D + tid];
    float bld = bl[tid];
    int start = offs[node], end = offs[node + 1];
    float acc = 0.f;
    for (int e0 = start; e0 < end; e0 += EB) {
        int nb = min(EB, end - e0);
        if (tid < nb) {
            int eid = perm[e0 + tid];
            s_eid[tid] = eid;
            s_src[tid] = ei[eid];
        }
        __syncthreads();
        for (int slot = tid; slot < nb * ED; slot += 256) {
            int e = slot >> 6, c = slot & 63;
            s_ea[e][c] = ea[(size_t)s_eid[e] * ED + c];
        }
        __syncthreads();
        for (int j = 0; j < nb; j++) {
            const float4* eap = (const float4*)&s_ea[j][0];
            float v = bld;
#pragma unroll
            for (int k4 = 0; k4 < ED / 4; k4++) {
                float4 e4 = eap[k4];
                v += e4.x * w[k4 * 4] + e4.y * w[k4 * 4 + 1] + e4.z * w[k4 * 4 + 2] + e4.w * w[k4 * 4 + 3];
            }
            v += x[(size_t)s_src[j] * D + tid];
            acc += fmaxf(v, 0.f);
        }
        __syncthreads();
    }
    size_t idx = (size_t)node * D + tid;
    h[idx] = (1.f + eps[0]) * x[idx] + acc;
}

// ---------------- generic fp32 GEMM ----------------
#define BM 64
#define BN 64
#define BK 16
template<int ACT, bool TRANSB>
__global__ __launch_bounds__(256) void gemm_kernel(
        const float* __restrict__ A, const float* __restrict__ B,
        const float* __restrict__ bias, float* __restrict__ C,
        int M, int K, int Nc) {
    __shared__ float As[BK][BM + 4];
    __shared__ float Bs[BK][BN + 4];
    int tid = threadIdx.x;
    int m0 = blockIdx.y * BM, n0 = blockIdx.x * BN;
    int tm = (tid >> 4) * 4, tn = (tid & 15) * 4;
    float acc[4][4] = {};
    for (int k0 = 0; k0 < K; k0 += BK) {
        int ac = tid & 15, ar = tid >> 4;
#pragma unroll
        for (int p = 0; p < 4; p++)
            As[ac][ar + p * 16] = A[(size_t)(m0 + ar + p * 16) * K + k0 + ac];
        if (TRANSB) {
            int bk = tid & 15, bj = tid >> 4;
#pragma unroll
            for (int p = 0; p < 4; p++)
                Bs[bk][bj + p * 16] = B[(size_t)(n0 + bj + p * 16) * K + k0 + bk];
        } else {
            int bj = tid & 63, bk = tid >> 6;
#pragma unroll
            for (int p = 0; p < 4; p++)
                Bs[bk + p * 4][bj] = B[(size_t)(k0 + bk + p * 4) * Nc + n0 + bj];
        }
        __syncthreads();
#pragma unroll
        for (int k = 0; k < BK; k++) {
            float4 a4 = *(const float4*)&As[k][tm];
            float4 b4 = *(const float4*)&Bs[k][tn];
            float a[4] = {a4.x, a4.y, a4.z, a4.w};
            float b[4] = {b4.x, b4.y, b4.z, b4.w};
#pragma unroll
            for (int i = 0; i < 4; i++)
#pragma unroll
                for (int j = 0; j < 4; j++) acc[i][j] += a[i] * b[j];
        }
        __syncthreads();
    }
#pragma unroll
    for (int i = 0; i < 4; i++) {
        float4 r;
        r.x = act_f<ACT>(acc[i][0] + bias[n0 + tn + 0]);
        r.y = act_f<ACT>(acc[i][1] + bias[n0 + tn + 1]);
        r.z = act_f<ACT>(acc[i][2] + bias[n0 + tn + 2]);
        r.w = act_f<ACT>(acc[i][3] + bias[n0 + tn + 3]);
        *(float4*)&C[(size_t)(m0 + tm + i) * Nc + n0 + tn] = r;
    }
}

// ---------------- row LayerNorm + optional ELU + residual ----------------
template<int ACT>
__global__ __launch_bounds__(256) void ln_res_kernel(
        const float* __restrict__ t, const float* __restrict__ res,
        const float* __restrict__ g, const float* __restrict__ b,
        float* __restrict__ out) {
    __shared__ float red[8];
    int row = blockIdx.x, tid = threadIdx.x;
    float v = t[(size_t)row * D + tid];
    int wid = tid >> 6, lane = tid & 63;
    float s = wave_sum(v);
    if (lane == 0) red[wid] = s;
    __syncthreads();
    float mu = (red[0] + red[1] + red[2] + red[3]) * (1.f / D);
    float dv = v - mu;
    float s2 = wave_sum(dv * dv);
    if (lane == 0) red[4 + wid] = s2;
    __syncthreads();
    float var = (red[4] + red[5] + red[6] + red[7]) * (1.f / D);
    float y = dv * rsqrtf(var + 1e-5f) * g[tid] + b[tid];
    y = act_f<ACT>(y);
    out[(size_t)row * D + tid] = res[(size_t)row * D + tid] + y;
}

// ---------------- MFMA flash attention (split-K partials) ----------------
#define KSTR 40
#define VSTR 136
#define ATILE 128
__global__ __launch_bounds__(256) void attn_mfma_kernel(
        const float* __restrict__ qkv, float* __restrict__ po,
        float* __restrict__ pm, float* __restrict__ pl, int N, int KC_) {
    __shared__ short Ks[ATILE * KSTR];
    __shared__ short VTs[HD * VSTR];
    const int tid = threadIdx.x;
    const int wave = tid >> 6, lane = tid & 63;
    const int mm = lane & 15, quad = lane >> 4;
    const int h = blockIdx.y, c = blockIdx.z;
    const int qbase = blockIdx.x * 64 + wave * 16;
    const float scale = 0.17677669529663687f; // 1/sqrt(32)

    short8 qf;
    {
        const float* qrow = qkv + (size_t)(qbase + mm) * (3 * D) + h * HD + quad * 8;
        float4 a = *(const float4*)qrow;
        float4 b = *(const float4*)(qrow + 4);
        qf[0] = f2bf(a.x * scale); qf[1] = f2bf(a.y * scale);
        qf[2] = f2bf(a.z * scale); qf[3] = f2bf(a.w * scale);
        qf[4] = f2bf(b.x * scale); qf[5] = f2bf(b.y * scale);
        qf[6] = f2bf(b.z * scale); qf[7] = f2bf(b.w * scale);
    }
    floatx4 accA = {0.f, 0.f, 0.f, 0.f};
    floatx4 accB = {0.f, 0.f, 0.f, 0.f};
    float m_r = -1e30f, l_r = 0.f;

    const int kchunk = N / KC_;
    const int kstart = c * kchunk;
    const int krow0 = ((mm >> 2) << 3) | (mm & 3);

    for (int t0 = 0; t0 < kchunk; t0 += ATILE) {
#pragma unroll
        for (int p = 0; p < 4; p++) {
            int slot = tid + p * 256;
            int kr = slot >> 3, e4 = slot & 7;
            const float* krow = qkv + (size_t)(kstart + t0 + kr) * (3 * D) + D + h * HD + e4 * 4;
            float4 kv = *(const float4*)krow;
            short4v ks;
            ks[0] = f2bf(kv.x); ks[1] = f2bf(kv.y); ks[2] = f2bf(kv.z); ks[3] = f2bf(kv.w);
            *(short4v*)&Ks[kr * KSTR + e4 * 4] = ks;
            const float* vrow = qkv + (size_t)(kstart + t0 + kr) * (3 * D) + 2 * D + h * HD + e4 * 4;
            float4 vv = *(const float4*)vrow;
            VTs[(e4 * 4 + 0) * VSTR + kr] = f2bf(vv.x);
            VTs[(e4 * 4 + 1) * VSTR + kr] = f2bf(vv.y);
            VTs[(e4 * 4 + 2) * VSTR + kr] = f2bf(vv.z);
            VTs[(e4 * 4 + 3) * VSTR + kr] = f2bf(vv.w);
        }
        __syncthreads();
#pragma unroll
        for (int s = 0; s < ATILE / 32; s++) {
            int sb = s * 32;
            short8 kf0 = *(const short8*)&Ks[(sb + krow0) * KSTR + quad * 8];
            short8 kf1 = *(const short8*)&Ks[(sb + krow0 + 4) * KSTR + quad * 8];
            floatx4 zero = {0.f, 0.f, 0.f, 0.f};
            floatx4 s0 = __builtin_amdgcn_mfma_f32_16x16x32_bf16(kf0, qf, zero, 0, 0, 0);
            floatx4 s1 = __builtin_amdgcn_mfma_f32_16x16x32_bf16(kf1, qf, zero, 0, 0, 0);
            float mx = fmaxf(fmaxf(fmaxf(s0[0], s0[1]), fmaxf(s0[2], s0[3])),
                             fmaxf(fmaxf(s1[0], s1[1]), fmaxf(s1[2], s1[3])));
            mx = fmaxf(mx, __shfl_xor(mx, 16));
            mx = fmaxf(mx, __shfl_xor(mx, 32));
            float nm = fmaxf(m_r, mx);
            float alpha = __expf(m_r - nm);
            float p0[4], p1[4], ls = 0.f;
#pragma unroll
            for (int j = 0; j < 4; j++) {
                p0[j] = __expf(s0[j] - nm);
                p1[j] = __expf(s1[j] - nm);
                ls += p0[j] + p1[j];
            }
            ls += __shfl_xor(ls, 16);
            ls += __shfl_xor(ls, 32);
            l_r = l_r * alpha + ls;
            m_r = nm;
            short8 pf;
#pragma unroll
            for (int j = 0; j < 4; j++) { pf[j] = f2bf(p0[j]); pf[4 + j] = f2bf(p1[j]); }
#pragma unroll
            for (int j = 0; j < 4; j++) { accA[j] *= alpha; accB[j] *= alpha; }
            short8 vf0 = *(const short8*)&VTs[mm * VSTR + sb + quad * 8];
            short8 vf1 = *(const short8*)&VTs[(mm + 16) * VSTR + sb + quad * 8];
            accA = __builtin_amdgcn_mfma_f32_16x16x32_bf16(vf0, pf, accA, 0, 0, 0);
            accB = __builtin_amdgcn_mfma_f32_16x16x32_bf16(vf1, pf, accB, 0, 0, 0);
        }
        __syncthreads();
    }
    size_t NH = (size_t)N * H;
    int qi = qbase + mm;
    size_t nh = (size_t)qi * H + h;
    if (lane < 16) {
        pm[(size_t)c * NH + nh] = m_r;
        pl[(size_t)c * NH + nh] = l_r;
    }
    float* op = po + ((size_t)c * NH + nh) * HD;
#pragma unroll
    for (int j = 0; j < 4; j++) {
        op[quad * 4 + j] = accA[j];
        op[16 + quad * 4 + j] = accB[j];
    }
}

// ---------------- combine partials -> obuf[N, 256] ----------------
__global__ __launch_bounds__(256) void attn_combine_kernel(
        const float* __restrict__ po, const float* __restrict__ pm,
        const float* __restrict__ pl, float* __restrict__ obuf, int N, int KC_) {
    int idx = blockIdx.x * 256 + threadIdx.x;
    int d = idx & (HD - 1);
    int nh = idx >> 5;
    size_t NH = (size_t)N * H;
    float M = -1e30f;
    for (int cc = 0; cc < KC_; cc++) M = fmaxf(M, pm[(size_t)cc * NH + nh]);
    float l = 0.f, o = 0.f;
    for (int cc = 0; cc < KC_; cc++) {
        float a = __expf(pm[(size_t)cc * NH + nh] - M);
        l += a * pl[(size_t)cc * NH + nh];
        o += a * po[((size_t)cc * NH + nh) * HD + d];
    }
    int n = nh >> 3, h = nh & (H - 1);
    obuf[(size_t)n * D + h * HD + d] = o / l;
}

// ---------------- launch ----------------
extern "C" void kernel_launch(void* const* d_in, const int* in_sizes, int n_in,
                              void* d_out, int out_size, void* d_ws, size_t ws_size,
                              hipStream_t stream) {
    const float* x    = (const float*)d_in[0];
    const int*   ei   = (const int*)d_in[1];
    const float* ea   = (const float*)d_in[2];
    const float* eps  = (const float*)d_in[3];
    const float* Wl   = (const float*)d_in[4];
    const float* bl   = (const float*)d_in[5];
    const float* W1   = (const float*)d_in[6];
    const float* b1   = (const float*)d_in[7];
    const float* W2   = (const float*)d_in[8];
    const float* b2   = (const float*)d_in[9];
    const float* lnlg = (const float*)d_in[10];
    const float* lnlb = (const float*)d_in[11];
    const float* in_w = (const float*)d_in[12];
    const float* in_b = (const float*)d_in[13];
    const float* outw = (const float*)d_in[14];
    const float* outb = (const float*)d_in[15];
    const float* lnag = (const float*)d_in[16];
    const float* lnab = (const float*)d_in[17];
    const float* Wf1  = (const float*)d_in[18];
    const float* bf1  = (const float*)d_in[19];
    const float* Wf2  = (const float*)d_in[20];
    const float* bf2  = (const float*)d_in[21];
    const float* lnfg = (const float*)d_in[22];
    const float* lnfb = (const float*)d_in[23];
    float* out = (float*)d_out;

    const int N = in_sizes[0] / D;       // 4096
    const int E = in_sizes[1] / 2;       // 262144
    const size_t NF = (size_t)N * D;     // 1048576

    auto need_bytes = [&](int kc) -> size_t {
        return ((size_t)(4 + kc) * NF + 2 * (size_t)kc * N * H) * sizeof(float)
             + (size_t)(2 * N + 1 + E + 4) * sizeof(int);
    };
    int KCsel = (ws_size >= need_bytes(4)) ? 4 : 2;

    float* w = (float*)d_ws;
    float* x1   = w;
    float* qkv  = w + NF;
    float* h    = w + 4 * NF;
    float* t1   = w + 5 * NF;
    float* t2   = w + 6 * NF;
    float* po   = w + 4 * NF;
    float* pm   = w + (4 + (size_t)KCsel) * NF;
    float* pl   = pm + (size_t)KCsel * N * H;
    float* obuf = w + NF;
    float* t3   = w + 2 * NF;
    float* x2   = w + 3 * NF;
    float* f1   = w + 4 * NF;
    float* f2   = w + 6 * NF;
    // int workspace (16B-aligned): cursor/cnt[N], perm[E], offs[N+1]
    int* ibase  = (int*)(pl + (size_t)KCsel * N * H);
    int* cnt    = ibase;            // doubles as scatter cursor after scan
    int* perm   = ibase + N;
    int* offs   = perm + E;

    // --- edge binning + aggregation ---
    zero_kernel<<<(N + 255) / 256, 256, 0, stream>>>(cnt, N);
    hist_kernel<<<(E + 255) / 256, 256, 0, stream>>>(ei, cnt, E);
    scan_kernel<<<1, 1024, 0, stream>>>(cnt, offs);
    scatter_kernel<<<(E + 255) / 256, 256, 0, stream>>>(ei, cnt, perm, E);
    agg_kernel<<<N, 256, 0, stream>>>(x, ei, ea, Wl, bl, eps, offs, perm, h, E);
    // --- local MLP ---
    gemm_kernel<2, false><<<dim3(D / BN, N / BM), 256, 0, stream>>>(h, W1, b1, t1, N, D, D);
    gemm_kernel<0, false><<<dim3(D / BN, N / BM), 256, 0, stream>>>(t1, W2, b2, t2, N, D, D);
    ln_res_kernel<2><<<N, 256, 0, stream>>>(t2, x, lnlg, lnlb, x1);
    // --- attention ---
    gemm_kernel<0, true><<<dim3(3 * D / BN, N / BM), 256, 0, stream>>>(x1, in_w, in_b, qkv, N, D, 3 * D);
    attn_mfma_kernel<<<dim3(N / 64, H, KCsel), 256, 0, stream>>>(qkv, po, pm, pl, N, KCsel);
    attn_combine_kernel<<<(int)(NF / 256), 256, 0, stream>>>(po, pm, pl, obuf, N, KCsel);
    gemm_kernel<0, true><<<dim3(D / BN, N / BM), 256, 0, stream>>>(obuf, outw, outb, t3, N, D, D);
    ln_res_kernel<0><<<N, 256, 0, stream>>>(t3, x1, lnag, lnab, x2);
    // --- FFN ---
    gemm_kernel<3, false><<<dim3(2 * D / BN, N / BM), 256, 0, stream>>>(x2, Wf1, bf1, f1, N, D, 2 * D);
    gemm_kernel<0, false><<<dim3(D / BN, N / BM), 256, 0, stream>>>(f1, Wf2, bf2, f2, N, 2 * D, D);
    ln_res_kernel<0><<<N, 256, 0, stream>>>(f2, x2, lnfg, lnfb, out);

    (void)n_in; (void)out_size; (void)ws_size;
}

// Round 5
// 547.570 us; speedup vs baseline: 1.2221x; 1.2221x over previous
//
#include <hip/hip_runtime.h>
#include <cstddef>

#define D 256
#define H 8
#define HD 32
#define ED 64
#define EB 16
#define EB2 32

typedef __attribute__((ext_vector_type(8))) short short8;
typedef __attribute__((ext_vector_type(4))) short short4v;
typedef __attribute__((ext_vector_type(4))) float floatx4;

// fp32 -> bf16 RNE
__device__ inline short f2bf(float f) {
    unsigned u = __float_as_uint(f);
    unsigned r = (u + 0x7fffu + ((u >> 16) & 1u)) >> 16;
    return (short)r;
}
__device__ inline float bf2f(short s) {
    return __uint_as_float(((unsigned)(unsigned short)s) << 16);
}

// ---------------- activations ----------------
template<int ACT> __device__ inline float act_f(float v) {
    if (ACT == 1) return fmaxf(v, 0.f);
    if (ACT == 2) return v > 0.f ? v : expm1f(v);              // elu
    if (ACT == 3) return 0.5f * v * (1.f + erff(v * 0.70710678118654752f)); // exact gelu
    return v;
}

__device__ inline float wave_sum(float v) {
#pragma unroll
    for (int off = 32; off > 0; off >>= 1) v += __shfl_xor(v, off, 64);
    return v;
}

// ================= edge binning pipeline =================
__global__ void zero_kernel(int* __restrict__ p, int n) {
    int i = blockIdx.x * 256 + threadIdx.x;
    if (i < n) p[i] = 0;
}

__global__ void hist_kernel(const int* __restrict__ ei, int* __restrict__ cnt, int E) {
    int e = blockIdx.x * 256 + threadIdx.x;
    if (e < E) atomicAdd(&cnt[ei[E + e]], 1);
}

// single block, 1024 threads, N=4096 counters -> exclusive offsets.
__global__ __launch_bounds__(1024) void scan_kernel(int* __restrict__ cnt,
                                                    int* __restrict__ offs) {
    __shared__ int s[1024];
    int tid = threadIdx.x;
    int4 c = *(int4*)&cnt[tid * 4];
    int sum = c.x + c.y + c.z + c.w;
    s[tid] = sum;
    __syncthreads();
    for (int off = 1; off < 1024; off <<= 1) {
        int v = (tid >= off) ? s[tid - off] : 0;
        __syncthreads();
        s[tid] += v;
        __syncthreads();
    }
    int ex = s[tid] - sum;
    int o1 = ex + c.x, o2 = o1 + c.y, o3 = o2 + c.z;
    offs[tid * 4] = ex; offs[tid * 4 + 1] = o1;
    offs[tid * 4 + 2] = o2; offs[tid * 4 + 3] = o3;
    cnt[tid * 4] = ex; cnt[tid * 4 + 1] = o1;
    cnt[tid * 4 + 2] = o2; cnt[tid * 4 + 3] = o3;
    if (tid == 1023) offs[4096] = s[1023];
}

__global__ void scatter_kernel(const int* __restrict__ ei, int* __restrict__ cursor,
                               int* __restrict__ perm, int* __restrict__ srcp, int E) {
    int e = blockIdx.x * 256 + threadIdx.x;
    if (e < E) {
        int pos = atomicAdd(&cursor[ei[E + e]], 1);
        perm[pos] = e;
        srcp[pos] = ei[e];
    }
}

// Wl [64][256] fp32 -> WlT [256][64] bf16
__global__ void wlT_kernel(const float* __restrict__ Wl, short* __restrict__ WlT) {
    int idx = blockIdx.x * 256 + threadIdx.x;   // 16384
    int n = idx >> 6, k = idx & 63;
    WlT[idx] = f2bf(Wl[k * D + n]);
}

// EL[i][:] = ea[perm[i]] @ Wl + bl  (bf16 out, permuted/binned row order)
// MFMA 16x16x32: A=WlT (m=EL col), B=ea (n=edge). Block: 64 edges x 256 cols.
__global__ __launch_bounds__(256) void el_gemm_kernel(
        const float* __restrict__ ea, const short* __restrict__ WlT,
        const float* __restrict__ bl, const int* __restrict__ perm,
        short* __restrict__ EL) {
    __shared__ __align__(16) short ea_s[64 * 72];
    __shared__ int s_perm[64];
    int tid = threadIdx.x;
    int wave = tid >> 6, lane = tid & 63;
    int mm = lane & 15, quad = lane >> 4;
    int e0 = blockIdx.x * 64;
    if (tid < 64) s_perm[tid] = perm[e0 + tid];
    __syncthreads();
#pragma unroll
    for (int p = 0; p < 4; p++) {
        int slot = tid + p * 256;
        int row = slot >> 4, c4 = slot & 15;
        float4 v = *(const float4*)&ea[(size_t)s_perm[row] * ED + c4 * 4];
        short4v s; s[0] = f2bf(v.x); s[1] = f2bf(v.y); s[2] = f2bf(v.z); s[3] = f2bf(v.w);
        *(short4v*)&ea_s[row * 72 + c4 * 4] = s;
    }
    __syncthreads();
    short8 af[4][2];
#pragma unroll
    for (int t = 0; t < 4; t++)
#pragma unroll
        for (int q2 = 0; q2 < 2; q2++)
            af[t][q2] = *(const short8*)&WlT[(wave * 64 + t * 16 + mm) * 64 + q2 * 32 + quad * 8];
    floatx4 acc[4][4];
#pragma unroll
    for (int et = 0; et < 4; et++)
#pragma unroll
        for (int t = 0; t < 4; t++) acc[et][t] = (floatx4){0.f, 0.f, 0.f, 0.f};
#pragma unroll
    for (int et = 0; et < 4; et++) {
        short8 bf0 = *(const short8*)&ea_s[(et * 16 + mm) * 72 + quad * 8];
        short8 bf1 = *(const short8*)&ea_s[(et * 16 + mm) * 72 + 32 + quad * 8];
#pragma unroll
        for (int t = 0; t < 4; t++) {
            acc[et][t] = __builtin_amdgcn_mfma_f32_16x16x32_bf16(af[t][0], bf0, acc[et][t], 0, 0, 0);
            acc[et][t] = __builtin_amdgcn_mfma_f32_16x16x32_bf16(af[t][1], bf1, acc[et][t], 0, 0, 0);
        }
    }
#pragma unroll
    for (int et = 0; et < 4; et++) {
        size_t edge = (size_t)(e0 + et * 16 + mm);
#pragma unroll
        for (int t = 0; t < 4; t++) {
            int col = wave * 64 + t * 16 + quad * 4;
            short4v r;
#pragma unroll
            for (int j = 0; j < 4; j++) r[j] = f2bf(acc[et][t][j] + bl[col + j]);
            *(short4v*)&EL[edge * D + col] = r;
        }
    }
}

// h[node] = (1+eps)*x[node] + sum_{bin} relu(EL_perm[i] + x[srcp[i]])
__global__ __launch_bounds__(256) void agg_el_kernel(
        const float* __restrict__ x, const short* __restrict__ EL,
        const float* __restrict__ eps, const int* __restrict__ offs,
        const int* __restrict__ srcp, float* __restrict__ h) {
    __shared__ int s_src[EB2];
    int node = blockIdx.x, tid = threadIdx.x;
    int start = offs[node], end = offs[node + 1];
    float acc = 0.f;
    for (int e0 = start; e0 < end; e0 += EB2) {
        int nb = min(EB2, end - e0);
        __syncthreads();
        if (tid < nb) s_src[tid] = srcp[e0 + tid];
        __syncthreads();
        for (int j = 0; j < nb; j++) {
            float el = bf2f(EL[(size_t)(e0 + j) * D + tid]);
            float v = el + x[(size_t)s_src[j] * D + tid];
            acc += fmaxf(v, 0.f);
        }
    }
    size_t idx = (size_t)node * D + tid;
    h[idx] = (1.f + eps[0]) * x[idx] + acc;
}

// ---- fallback (small ws): fused compute agg, one block per node ----
__global__ __launch_bounds__(256) void agg_kernel(
        const float* __restrict__ x, const int* __restrict__ ei,
        const float* __restrict__ ea, const float* __restrict__ Wl,
        const float* __restrict__ bl, const float* __restrict__ eps,
        const int* __restrict__ offs, const int* __restrict__ perm,
        float* __restrict__ h, int E) {
    __shared__ float s_ea[EB][ED];
    __shared__ int s_src[EB], s_eid[EB];
    int node = blockIdx.x, tid = threadIdx.x;
    float w[ED];
#pragma unroll
    for (int k = 0; k < ED; k++) w[k] = Wl[k * D + tid];
    float bld = bl[tid];
    int start = offs[node], end = offs[node + 1];
    float acc = 0.f;
    for (int e0 = start; e0 < end; e0 += EB) {
        int nb = min(EB, end - e0);
        if (tid < nb) {
            int eid = perm[e0 + tid];
            s_eid[tid] = eid;
            s_src[tid] = ei[eid];
        }
        __syncthreads();
        for (int slot = tid; slot < nb * ED; slot += 256) {
            int e = slot >> 6, c = slot & 63;
            s_ea[e][c] = ea[(size_t)s_eid[e] * ED + c];
        }
        __syncthreads();
        for (int j = 0; j < nb; j++) {
            const float4* eap = (const float4*)&s_ea[j][0];
            float v = bld;
#pragma unroll
            for (int k4 = 0; k4 < ED / 4; k4++) {
                float4 e4 = eap[k4];
                v += e4.x * w[k4 * 4] + e4.y * w[k4 * 4 + 1] + e4.z * w[k4 * 4 + 2] + e4.w * w[k4 * 4 + 3];
            }
            v += x[(size_t)s_src[j] * D + tid];
            acc += fmaxf(v, 0.f);
        }
        __syncthreads();
    }
    size_t idx = (size_t)node * D + tid;
    h[idx] = (1.f + eps[0]) * x[idx] + acc;
}

// ---------------- generic fp32 GEMM ----------------
#define BM 64
#define BN 64
#define BK 16
template<int ACT, bool TRANSB>
__global__ __launch_bounds__(256) void gemm_kernel(
        const float* __restrict__ A, const float* __restrict__ B,
        const float* __restrict__ bias, float* __restrict__ C,
        int M, int K, int Nc) {
    __shared__ float As[BK][BM + 4];
    __shared__ float Bs[BK][BN + 4];
    int tid = threadIdx.x;
    int m0 = blockIdx.y * BM, n0 = blockIdx.x * BN;
    int tm = (tid >> 4) * 4, tn = (tid & 15) * 4;
    float acc[4][4] = {};
    for (int k0 = 0; k0 < K; k0 += BK) {
        int ac = tid & 15, ar = tid >> 4;
#pragma unroll
        for (int p = 0; p < 4; p++)
            As[ac][ar + p * 16] = A[(size_t)(m0 + ar + p * 16) * K + k0 + ac];
        if (TRANSB) {
            int bk = tid & 15, bj = tid >> 4;
#pragma unroll
            for (int p = 0; p < 4; p++)
                Bs[bk][bj + p * 16] = B[(size_t)(n0 + bj + p * 16) * K + k0 + bk];
        } else {
            int bj = tid & 63, bk = tid >> 6;
#pragma unroll
            for (int p = 0; p < 4; p++)
                Bs[bk + p * 4][bj] = B[(size_t)(k0 + bk + p * 4) * Nc + n0 + bj];
        }
        __syncthreads();
#pragma unroll
        for (int k = 0; k < BK; k++) {
            float4 a4 = *(const float4*)&As[k][tm];
            float4 b4 = *(const float4*)&Bs[k][tn];
            float a[4] = {a4.x, a4.y, a4.z, a4.w};
            float b[4] = {b4.x, b4.y, b4.z, b4.w};
#pragma unroll
            for (int i = 0; i < 4; i++)
#pragma unroll
                for (int j = 0; j < 4; j++) acc[i][j] += a[i] * b[j];
        }
        __syncthreads();
    }
#pragma unroll
    for (int i = 0; i < 4; i++) {
        float4 r;
        r.x = act_f<ACT>(acc[i][0] + bias[n0 + tn + 0]);
        r.y = act_f<ACT>(acc[i][1] + bias[n0 + tn + 1]);
        r.z = act_f<ACT>(acc[i][2] + bias[n0 + tn + 2]);
        r.w = act_f<ACT>(acc[i][3] + bias[n0 + tn + 3]);
        *(float4*)&C[(size_t)(m0 + tm + i) * Nc + n0 + tn] = r;
    }
}

// ---------------- row LayerNorm + optional ELU + residual ----------------
template<int ACT>
__global__ __launch_bounds__(256) void ln_res_kernel(
        const float* __restrict__ t, const float* __restrict__ res,
        const float* __restrict__ g, const float* __restrict__ b,
        float* __restrict__ out) {
    __shared__ float red[8];
    int row = blockIdx.x, tid = threadIdx.x;
    float v = t[(size_t)row * D + tid];
    int wid = tid >> 6, lane = tid & 63;
    float s = wave_sum(v);
    if (lane == 0) red[wid] = s;
    __syncthreads();
    float mu = (red[0] + red[1] + red[2] + red[3]) * (1.f / D);
    float dv = v - mu;
    float s2 = wave_sum(dv * dv);
    if (lane == 0) red[4 + wid] = s2;
    __syncthreads();
    float var = (red[4] + red[5] + red[6] + red[7]) * (1.f / D);
    float y = dv * rsqrtf(var + 1e-5f) * g[tid] + b[tid];
    y = act_f<ACT>(y);
    out[(size_t)row * D + tid] = res[(size_t)row * D + tid] + y;
}

// ---------------- MFMA flash attention (split-K partials) ----------------
#define KSTR 40
#define VSTR 136
#define ATILE 128
__global__ __launch_bounds__(256) void attn_mfma_kernel(
        const float* __restrict__ qkv, float* __restrict__ po,
        float* __restrict__ pm, float* __restrict__ pl, int N, int KC_) {
    __shared__ __align__(16) short Ks[ATILE * KSTR];
    __shared__ __align__(16) short VTs[HD * VSTR];
    const int tid = threadIdx.x;
    const int wave = tid >> 6, lane = tid & 63;
    const int mm = lane & 15, quad = lane >> 4;
    const int h = blockIdx.y, c = blockIdx.z;
    const int qbase = blockIdx.x * 64 + wave * 16;
    const float scale = 0.17677669529663687f; // 1/sqrt(32)

    short8 qf;
    {
        const float* qrow = qkv + (size_t)(qbase + mm) * (3 * D) + h * HD + quad * 8;
        float4 a = *(const float4*)qrow;
        float4 b = *(const float4*)(qrow + 4);
        qf[0] = f2bf(a.x * scale); qf[1] = f2bf(a.y * scale);
        qf[2] = f2bf(a.z * scale); qf[3] = f2bf(a.w * scale);
        qf[4] = f2bf(b.x * scale); qf[5] = f2bf(b.y * scale);
        qf[6] = f2bf(b.z * scale); qf[7] = f2bf(b.w * scale);
    }
    floatx4 accA = {0.f, 0.f, 0.f, 0.f};
    floatx4 accB = {0.f, 0.f, 0.f, 0.f};
    float m_r = -1e30f, l_r = 0.f;

    const int kchunk = N / KC_;
    const int kstart = c * kchunk;
    const int krow0 = ((mm >> 2) << 3) | (mm & 3);

    for (int t0 = 0; t0 < kchunk; t0 += ATILE) {
#pragma unroll
        for (int p = 0; p < 4; p++) {
            int slot = tid + p * 256;
            int kr = slot >> 3, e4 = slot & 7;
            const float* krow = qkv + (size_t)(kstart + t0 + kr) * (3 * D) + D + h * HD + e4 * 4;
            float4 kv = *(const float4*)krow;
            short4v ks;
            ks[0] = f2bf(kv.x); ks[1] = f2bf(kv.y); ks[2] = f2bf(kv.z); ks[3] = f2bf(kv.w);
            *(short4v*)&Ks[kr * KSTR + e4 * 4] = ks;
            const float* vrow = qkv + (size_t)(kstart + t0 + kr) * (3 * D) + 2 * D + h * HD + e4 * 4;
            float4 vv = *(const float4*)vrow;
            VTs[(e4 * 4 + 0) * VSTR + kr] = f2bf(vv.x);
            VTs[(e4 * 4 + 1) * VSTR + kr] = f2bf(vv.y);
            VTs[(e4 * 4 + 2) * VSTR + kr] = f2bf(vv.z);
            VTs[(e4 * 4 + 3) * VSTR + kr] = f2bf(vv.w);
        }
        __syncthreads();
#pragma unroll
        for (int s = 0; s < ATILE / 32; s++) {
            int sb = s * 32;
            short8 kf0 = *(const short8*)&Ks[(sb + krow0) * KSTR + quad * 8];
            short8 kf1 = *(const short8*)&Ks[(sb + krow0 + 4) * KSTR + quad * 8];
            floatx4 zero = {0.f, 0.f, 0.f, 0.f};
            floatx4 s0 = __builtin_amdgcn_mfma_f32_16x16x32_bf16(kf0, qf, zero, 0, 0, 0);
            floatx4 s1 = __builtin_amdgcn_mfma_f32_16x16x32_bf16(kf1, qf, zero, 0, 0, 0);
            float mx = fmaxf(fmaxf(fmaxf(s0[0], s0[1]), fmaxf(s0[2], s0[3])),
                             fmaxf(fmaxf(s1[0], s1[1]), fmaxf(s1[2], s1[3])));
            mx = fmaxf(mx, __shfl_xor(mx, 16));
            mx = fmaxf(mx, __shfl_xor(mx, 32));
            float nm = fmaxf(m_r, mx);
            float alpha = __expf(m_r - nm);
            float p0[4], p1[4], ls = 0.f;
#pragma unroll
            for (int j = 0; j < 4; j++) {
                p0[j] = __expf(s0[j] - nm);
                p1[j] = __expf(s1[j] - nm);
                ls += p0[j] + p1[j];
            }
            ls += __shfl_xor(ls, 16);
            ls += __shfl_xor(ls, 32);
            l_r = l_r * alpha + ls;
            m_r = nm;
            short8 pf;
#pragma unroll
            for (int j = 0; j < 4; j++) { pf[j] = f2bf(p0[j]); pf[4 + j] = f2bf(p1[j]); }
#pragma unroll
            for (int j = 0; j < 4; j++) { accA[j] *= alpha; accB[j] *= alpha; }
            short8 vf0 = *(const short8*)&VTs[mm * VSTR + sb + quad * 8];
            short8 vf1 = *(const short8*)&VTs[(mm + 16) * VSTR + sb + quad * 8];
            accA = __builtin_amdgcn_mfma_f32_16x16x32_bf16(vf0, pf, accA, 0, 0, 0);
            accB = __builtin_amdgcn_mfma_f32_16x16x32_bf16(vf1, pf, accB, 0, 0, 0);
        }
        __syncthreads();
    }
    size_t NH = (size_t)N * H;
    int qi = qbase + mm;
    size_t nh = (size_t)qi * H + h;
    if (lane < 16) {
        pm[(size_t)c * NH + nh] = m_r;
        pl[(size_t)c * NH + nh] = l_r;
    }
    float* op = po + ((size_t)c * NH + nh) * HD;
#pragma unroll
    for (int j = 0; j < 4; j++) {
        op[quad * 4 + j] = accA[j];
        op[16 + quad * 4 + j] = accB[j];
    }
}

// ---------------- combine partials -> obuf[N, 256] ----------------
__global__ __launch_bounds__(256) void attn_combine_kernel(
        const float* __restrict__ po, const float* __restrict__ pm,
        const float* __restrict__ pl, float* __restrict__ obuf, int N, int KC_) {
    int idx = blockIdx.x * 256 + threadIdx.x;
    int d = idx & (HD - 1);
    int nh = idx >> 5;
    size_t NH = (size_t)N * H;
    float M = -1e30f;
    for (int cc = 0; cc < KC_; cc++) M = fmaxf(M, pm[(size_t)cc * NH + nh]);
    float l = 0.f, o = 0.f;
    for (int cc = 0; cc < KC_; cc++) {
        float a = __expf(pm[(size_t)cc * NH + nh] - M);
        l += a * pl[(size_t)cc * NH + nh];
        o += a * po[((size_t)cc * NH + nh) * HD + d];
    }
    int n = nh >> 3, h = nh & (H - 1);
    obuf[(size_t)n * D + h * HD + d] = o / l;
}

// ---------------- launch ----------------
extern "C" void kernel_launch(void* const* d_in, const int* in_sizes, int n_in,
                              void* d_out, int out_size, void* d_ws, size_t ws_size,
                              hipStream_t stream) {
    const float* x    = (const float*)d_in[0];
    const int*   ei   = (const int*)d_in[1];
    const float* ea   = (const float*)d_in[2];
    const float* eps  = (const float*)d_in[3];
    const float* Wl   = (const float*)d_in[4];
    const float* bl   = (const float*)d_in[5];
    const float* W1   = (const float*)d_in[6];
    const float* b1   = (const float*)d_in[7];
    const float* W2   = (const float*)d_in[8];
    const float* b2   = (const float*)d_in[9];
    const float* lnlg = (const float*)d_in[10];
    const float* lnlb = (const float*)d_in[11];
    const float* in_w = (const float*)d_in[12];
    const float* in_b = (const float*)d_in[13];
    const float* outw = (const float*)d_in[14];
    const float* outb = (const float*)d_in[15];
    const float* lnag = (const float*)d_in[16];
    const float* lnab = (const float*)d_in[17];
    const float* Wf1  = (const float*)d_in[18];
    const float* bf1  = (const float*)d_in[19];
    const float* Wf2  = (const float*)d_in[20];
    const float* bf2  = (const float*)d_in[21];
    const float* lnfg = (const float*)d_in[22];
    const float* lnfb = (const float*)d_in[23];
    float* out = (float*)d_out;

    const int N = in_sizes[0] / D;       // 4096
    const int E = in_sizes[1] / 2;       // 262144
    const size_t NF = (size_t)N * D;     // 1048576
    const size_t NH = (size_t)N * H;

    int KCsel = 4;
    // float region: x1(1) qkv(3) then h/t1/t2 overlapped with po(KC); pm/pl after
    size_t floatEnd = (4 + (size_t)KCsel) * NF + 2 * (size_t)KCsel * NH;
    size_t intCount = (size_t)N + 2 * (size_t)E + (size_t)(N + 1);   // cnt, perm, srcp, offs
    size_t offB = floatEnd * 4;
    offB = (offB + 15) & ~(size_t)15;
    size_t elOff = offB;                       // EL bf16 region
    size_t elBytes = (size_t)E * D * 2;
    size_t intOff = (elOff + elBytes + 15) & ~(size_t)15;
    size_t wltOff = (intOff + intCount * 4 + 15) & ~(size_t)15;
    size_t needEL = wltOff + 16384 * 2;
    // fallback layout (no EL)
    size_t intOffFB = offB;
    size_t needFB = intOffFB + intCount * 4;
    bool useEL = (ws_size >= needEL);

    float* w = (float*)d_ws;
    float* x1   = w;
    float* qkv  = w + NF;
    float* h    = w + 4 * NF;
    float* t1   = w + 5 * NF;
    float* t2   = w + 6 * NF;
    float* po   = w + 4 * NF;
    float* pm   = w + (4 + (size_t)KCsel) * NF;
    float* pl   = pm + (size_t)KCsel * NH;
    float* obuf = w + NF;
    float* t3   = w + 2 * NF;
    float* x2   = w + 3 * NF;
    float* f1   = w + 4 * NF;
    float* f2   = w + 6 * NF;

    char* base = (char*)d_ws;
    short* EL   = (short*)(base + elOff);
    int* ibase  = (int*)(base + (useEL ? intOff : intOffFB));
    int* cnt    = ibase;
    int* perm   = ibase + N;
    int* srcp   = perm + E;
    int* offs   = srcp + E;
    short* WlT  = (short*)(base + wltOff);
    (void)needFB;

    // --- edge binning ---
    zero_kernel<<<(N + 255) / 256, 256, 0, stream>>>(cnt, N);
    hist_kernel<<<(E + 255) / 256, 256, 0, stream>>>(ei, cnt, E);
    scan_kernel<<<1, 1024, 0, stream>>>(cnt, offs);
    scatter_kernel<<<(E + 255) / 256, 256, 0, stream>>>(ei, cnt, perm, srcp, E);
    if (useEL) {
        wlT_kernel<<<64, 256, 0, stream>>>(Wl, WlT);
        el_gemm_kernel<<<E / 64, 256, 0, stream>>>(ea, WlT, bl, perm, EL);
        agg_el_kernel<<<N, 256, 0, stream>>>(x, EL, eps, offs, srcp, h);
    } else {
        agg_kernel<<<N, 256, 0, stream>>>(x, ei, ea, Wl, bl, eps, offs, perm, h, E);
    }
    // --- local MLP ---
    gemm_kernel<2, false><<<dim3(D / BN, N / BM), 256, 0, stream>>>(h, W1, b1, t1, N, D, D);
    gemm_kernel<0, false><<<dim3(D / BN, N / BM), 256, 0, stream>>>(t1, W2, b2, t2, N, D, D);
    ln_res_kernel<2><<<N, 256, 0, stream>>>(t2, x, lnlg, lnlb, x1);
    // --- attention ---
    gemm_kernel<0, true><<<dim3(3 * D / BN, N / BM), 256, 0, stream>>>(x1, in_w, in_b, qkv, N, D, 3 * D);
    attn_mfma_kernel<<<dim3(N / 64, H, KCsel), 256, 0, stream>>>(qkv, po, pm, pl, N, KCsel);
    attn_combine_kernel<<<(int)(NF / 256), 256, 0, stream>>>(po, pm, pl, obuf, N, KCsel);
    gemm_kernel<0, true><<<dim3(D / BN, N / BM), 256, 0, stream>>>(obuf, outw, outb, t3, N, D, D);
    ln_res_kernel<0><<<N, 256, 0, stream>>>(t3, x1, lnag, lnab, x2);
    // --- FFN ---
    gemm_kernel<3, false><<<dim3(2 * D / BN, N / BM), 256, 0, stream>>>(x2, Wf1, bf1, f1, N, D, 2 * D);
    gemm_kernel<0, false><<<dim3(D / BN, N / BM), 256, 0, stream>>>(f1, Wf2, bf2, f2, N, 2 * D, D);
    ln_res_kernel<0><<<N, 256, 0, stream>>>(f2, x2, lnfg, lnfb, out);

    (void)n_in; (void)out_size;
}

// Round 6
// 544.633 us; speedup vs baseline: 1.2287x; 1.0054x over previous
//
#include <hip/hip_runtime.h>
#include <cstddef>

#define D 256
#define H 8
#define HD 32
#define ED 64

typedef __attribute__((ext_vector_type(8))) short short8;
typedef __attribute__((ext_vector_type(4))) short short4v;
typedef __attribute__((ext_vector_type(4))) float floatx4;

// fp32 -> bf16 RNE
__device__ inline short f2bf(float f) {
    unsigned u = __float_as_uint(f);
    unsigned r = (u + 0x7fffu + ((u >> 16) & 1u)) >> 16;
    return (short)r;
}

// ---------------- activations ----------------
template<int ACT> __device__ inline float act_f(float v) {
    if (ACT == 1) return fmaxf(v, 0.f);
    if (ACT == 2) return v > 0.f ? v : expm1f(v);              // elu
    if (ACT == 3) return 0.5f * v * (1.f + erff(v * 0.70710678118654752f)); // exact gelu
    return v;
}

__device__ inline float wave_sum(float v) {
#pragma unroll
    for (int off = 32; off > 0; off >>= 1) v += __shfl_xor(v, off, 64);
    return v;
}

// ================= edge binning pipeline =================
__global__ void zero_kernel(int* __restrict__ p, int n) {
    int i = blockIdx.x * 256 + threadIdx.x;
    if (i < n) p[i] = 0;
}

__global__ void hist_kernel(const int* __restrict__ ei, int* __restrict__ cnt, int E) {
    int e = blockIdx.x * 256 + threadIdx.x;
    if (e < E) atomicAdd(&cnt[ei[E + e]], 1);
}

// single block, 1024 threads, N=4096 counters -> exclusive offsets.
__global__ __launch_bounds__(1024) void scan_kernel(int* __restrict__ cnt,
                                                    int* __restrict__ offs) {
    __shared__ int s[1024];
    int tid = threadIdx.x;
    int4 c = *(int4*)&cnt[tid * 4];
    int sum = c.x + c.y + c.z + c.w;
    s[tid] = sum;
    __syncthreads();
    for (int off = 1; off < 1024; off <<= 1) {
        int v = (tid >= off) ? s[tid - off] : 0;
        __syncthreads();
        s[tid] += v;
        __syncthreads();
    }
    int ex = s[tid] - sum;
    int o1 = ex + c.x, o2 = o1 + c.y, o3 = o2 + c.z;
    offs[tid * 4] = ex; offs[tid * 4 + 1] = o1;
    offs[tid * 4 + 2] = o2; offs[tid * 4 + 3] = o3;
    cnt[tid * 4] = ex; cnt[tid * 4 + 1] = o1;
    cnt[tid * 4 + 2] = o2; cnt[tid * 4 + 3] = o3;
    if (tid == 1023) offs[4096] = s[1023];
}

__global__ void scatter_kernel(const int* __restrict__ ei, int* __restrict__ cursor,
                               int* __restrict__ perm, int* __restrict__ srcp,
                               int* __restrict__ dstp, int E) {
    int e = blockIdx.x * 256 + threadIdx.x;
    if (e < E) {
        int d = ei[E + e];
        int pos = atomicAdd(&cursor[d], 1);
        perm[pos] = e;
        srcp[pos] = ei[e];
        dstp[pos] = d;
    }
}

// Wl [64][256] fp32 -> WlT [256][64] bf16
__global__ void wlT_kernel(const float* __restrict__ Wl, short* __restrict__ WlT) {
    int idx = blockIdx.x * 256 + threadIdx.x;   // 16384
    int n = idx >> 6, k = idx & 63;
    WlT[idx] = f2bf(Wl[k * D + n]);
}

// h = (1+eps)*x  (aggregation base)
__global__ void init_h_kernel(const float* __restrict__ x, const float* __restrict__ eps,
                              float* __restrict__ h, int total) {
    int i = blockIdx.x * 256 + threadIdx.x;
    if (i < total) h[i] = (1.f + eps[0]) * x[i];
}

// Fused: per block of 64 permuted edges -> MFMA edge-linear (64x256 tile) +
// bias + x[src] gather + relu in registers + segment-sum over same-dst runs,
// atomicAdd spill into h. Edges are sorted by dst, so runs are contiguous.
__global__ __launch_bounds__(256) void edge_fused_kernel(
        const float* __restrict__ ea, const short* __restrict__ WlT,
        const float* __restrict__ bl, const float* __restrict__ x,
        const int* __restrict__ perm, const int* __restrict__ srcp,
        const int* __restrict__ dstp, float* __restrict__ h) {
    __shared__ __align__(16) short ea_s[64 * 72];
    __shared__ int s_src[64], s_dst[64];
    int tid = threadIdx.x;
    int wave = tid >> 6, lane = tid & 63;
    int mm = lane & 15, quad = lane >> 4;
    int e0 = blockIdx.x * 64;
    if (tid < 64) {
        s_src[tid] = srcp[e0 + tid];
        s_dst[tid] = dstp[e0 + tid];
    }
    // stage ea rows (permuted) as bf16 B-operand
    {
        __shared__ int s_perm[64];
        if (tid >= 64 && tid < 128) s_perm[tid - 64] = perm[e0 + tid - 64];
        __syncthreads();
#pragma unroll
        for (int p = 0; p < 4; p++) {
            int slot = tid + p * 256;
            int row = slot >> 4, c4 = slot & 15;
            float4 v = *(const float4*)&ea[(size_t)s_perm[row] * ED + c4 * 4];
            short4v s; s[0] = f2bf(v.x); s[1] = f2bf(v.y); s[2] = f2bf(v.z); s[3] = f2bf(v.w);
            *(short4v*)&ea_s[row * 72 + c4 * 4] = s;
        }
    }
    __syncthreads();
    // A fragments: WlT rows = output col (this wave covers cols wave*64..+64)
    short8 af[4][2];
#pragma unroll
    for (int t = 0; t < 4; t++)
#pragma unroll
        for (int q2 = 0; q2 < 2; q2++)
            af[t][q2] = *(const short8*)&WlT[(wave * 64 + t * 16 + mm) * 64 + q2 * 32 + quad * 8];
    floatx4 acc[4][4];
#pragma unroll
    for (int et = 0; et < 4; et++)
#pragma unroll
        for (int t = 0; t < 4; t++) acc[et][t] = (floatx4){0.f, 0.f, 0.f, 0.f};
#pragma unroll
    for (int et = 0; et < 4; et++) {
        short8 bf0 = *(const short8*)&ea_s[(et * 16 + mm) * 72 + quad * 8];
        short8 bf1 = *(const short8*)&ea_s[(et * 16 + mm) * 72 + 32 + quad * 8];
#pragma unroll
        for (int t = 0; t < 4; t++) {
            acc[et][t] = __builtin_amdgcn_mfma_f32_16x16x32_bf16(af[t][0], bf0, acc[et][t], 0, 0, 0);
            acc[et][t] = __builtin_amdgcn_mfma_f32_16x16x32_bf16(af[t][1], bf1, acc[et][t], 0, 0, 0);
        }
    }
    // bias
    float4 blv[4];
#pragma unroll
    for (int t = 0; t < 4; t++)
        blv[t] = *(const float4*)&bl[wave * 64 + t * 16 + quad * 4];
    // + x[src] gather, relu  (lane: edge et*16+mm, cols wave*64+t*16+quad*4+j)
#pragma unroll
    for (int et = 0; et < 4; et++) {
        const float* xrow = x + (size_t)s_src[et * 16 + mm] * D + wave * 64 + quad * 4;
#pragma unroll
        for (int t = 0; t < 4; t++) {
            float4 xv = *(const float4*)(xrow + t * 16);
            acc[et][t][0] = fmaxf(acc[et][t][0] + blv[t].x + xv.x, 0.f);
            acc[et][t][1] = fmaxf(acc[et][t][1] + blv[t].y + xv.y, 0.f);
            acc[et][t][2] = fmaxf(acc[et][t][2] + blv[t].z + xv.z, 0.f);
            acc[et][t][3] = fmaxf(acc[et][t][3] + blv[t].w + xv.w, 0.f);
        }
    }
    // segment sum over same-dst runs (wave-uniform scan of s_dst)
    int segstart = 0;
    while (segstart < 64) {
        int segdst = s_dst[segstart];
        int segend = segstart + 1;
        while (segend < 64 && s_dst[segend] == segdst) segend++;
        int el0 = 0 * 16 + mm, el1 = 1 * 16 + mm, el2 = 2 * 16 + mm, el3 = 3 * 16 + mm;
        bool in0 = (el0 >= segstart) & (el0 < segend);
        bool in1 = (el1 >= segstart) & (el1 < segend);
        bool in2 = (el2 >= segstart) & (el2 < segend);
        bool in3 = (el3 >= segstart) & (el3 < segend);
        float* hrow = h + (size_t)segdst * D + wave * 64;
#pragma unroll
        for (int t = 0; t < 4; t++) {
#pragma unroll
            for (int j = 0; j < 4; j++) {
                float v = (in0 ? acc[0][t][j] : 0.f) + (in1 ? acc[1][t][j] : 0.f)
                        + (in2 ? acc[2][t][j] : 0.f) + (in3 ? acc[3][t][j] : 0.f);
                v += __shfl_xor(v, 1);
                v += __shfl_xor(v, 2);
                v += __shfl_xor(v, 4);
                v += __shfl_xor(v, 8);
                if (mm == 0) atomicAdd(&hrow[t * 16 + quad * 4 + j], v);
            }
        }
        segstart = segend;
    }
}

// ---------------- generic fp32 GEMM ----------------
#define BM 64
#define BN 64
#define BK 16
template<int ACT, bool TRANSB>
__global__ __launch_bounds__(256) void gemm_kernel(
        const float* __restrict__ A, const float* __restrict__ B,
        const float* __restrict__ bias, float* __restrict__ C,
        int M, int K, int Nc) {
    __shared__ float As[BK][BM + 4];
    __shared__ float Bs[BK][BN + 4];
    int tid = threadIdx.x;
    int m0 = blockIdx.y * BM, n0 = blockIdx.x * BN;
    int tm = (tid >> 4) * 4, tn = (tid & 15) * 4;
    float acc[4][4] = {};
    for (int k0 = 0; k0 < K; k0 += BK) {
        int ac = tid & 15, ar = tid >> 4;
#pragma unroll
        for (int p = 0; p < 4; p++)
            As[ac][ar + p * 16] = A[(size_t)(m0 + ar + p * 16) * K + k0 + ac];
        if (TRANSB) {
            int bk = tid & 15, bj = tid >> 4;
#pragma unroll
            for (int p = 0; p < 4; p++)
                Bs[bk][bj + p * 16] = B[(size_t)(n0 + bj + p * 16) * K + k0 + bk];
        } else {
            int bj = tid & 63, bk = tid >> 6;
#pragma unroll
            for (int p = 0; p < 4; p++)
                Bs[bk + p * 4][bj] = B[(size_t)(k0 + bk + p * 4) * Nc + n0 + bj];
        }
        __syncthreads();
#pragma unroll
        for (int k = 0; k < BK; k++) {
            float4 a4 = *(const float4*)&As[k][tm];
            float4 b4 = *(const float4*)&Bs[k][tn];
            float a[4] = {a4.x, a4.y, a4.z, a4.w};
            float b[4] = {b4.x, b4.y, b4.z, b4.w};
#pragma unroll
            for (int i = 0; i < 4; i++)
#pragma unroll
                for (int j = 0; j < 4; j++) acc[i][j] += a[i] * b[j];
        }
        __syncthreads();
    }
#pragma unroll
    for (int i = 0; i < 4; i++) {
        float4 r;
        r.x = act_f<ACT>(acc[i][0] + bias[n0 + tn + 0]);
        r.y = act_f<ACT>(acc[i][1] + bias[n0 + tn + 1]);
        r.z = act_f<ACT>(acc[i][2] + bias[n0 + tn + 2]);
        r.w = act_f<ACT>(acc[i][3] + bias[n0 + tn + 3]);
        *(float4*)&C[(size_t)(m0 + tm + i) * Nc + n0 + tn] = r;
    }
}

// ---------------- row LayerNorm + optional ELU + residual ----------------
template<int ACT>
__global__ __launch_bounds__(256) void ln_res_kernel(
        const float* __restrict__ t, const float* __restrict__ res,
        const float* __restrict__ g, const float* __restrict__ b,
        float* __restrict__ out) {
    __shared__ float red[8];
    int row = blockIdx.x, tid = threadIdx.x;
    float v = t[(size_t)row * D + tid];
    int wid = tid >> 6, lane = tid & 63;
    float s = wave_sum(v);
    if (lane == 0) red[wid] = s;
    __syncthreads();
    float mu = (red[0] + red[1] + red[2] + red[3]) * (1.f / D);
    float dv = v - mu;
    float s2 = wave_sum(dv * dv);
    if (lane == 0) red[4 + wid] = s2;
    __syncthreads();
    float var = (red[4] + red[5] + red[6] + red[7]) * (1.f / D);
    float y = dv * rsqrtf(var + 1e-5f) * g[tid] + b[tid];
    y = act_f<ACT>(y);
    out[(size_t)row * D + tid] = res[(size_t)row * D + tid] + y;
}

// ---------------- MFMA flash attention (split-K partials) ----------------
#define KSTR 40
#define VSTR 136
#define ATILE 128
__global__ __launch_bounds__(256) void attn_mfma_kernel(
        const float* __restrict__ qkv, float* __restrict__ po,
        float* __restrict__ pm, float* __restrict__ pl, int N, int KC_) {
    __shared__ __align__(16) short Ks[ATILE * KSTR];
    __shared__ __align__(16) short VTs[HD * VSTR];
    const int tid = threadIdx.x;
    const int wave = tid >> 6, lane = tid & 63;
    const int mm = lane & 15, quad = lane >> 4;
    const int h = blockIdx.y, c = blockIdx.z;
    const int qbase = blockIdx.x * 64 + wave * 16;
    const float scale = 0.17677669529663687f; // 1/sqrt(32)

    short8 qf;
    {
        const float* qrow = qkv + (size_t)(qbase + mm) * (3 * D) + h * HD + quad * 8;
        float4 a = *(const float4*)qrow;
        float4 b = *(const float4*)(qrow + 4);
        qf[0] = f2bf(a.x * scale); qf[1] = f2bf(a.y * scale);
        qf[2] = f2bf(a.z * scale); qf[3] = f2bf(a.w * scale);
        qf[4] = f2bf(b.x * scale); qf[5] = f2bf(b.y * scale);
        qf[6] = f2bf(b.z * scale); qf[7] = f2bf(b.w * scale);
    }
    floatx4 accA = {0.f, 0.f, 0.f, 0.f};
    floatx4 accB = {0.f, 0.f, 0.f, 0.f};
    float m_r = -1e30f, l_r = 0.f;

    const int kchunk = N / KC_;
    const int kstart = c * kchunk;
    const int krow0 = ((mm >> 2) << 3) | (mm & 3);

    for (int t0 = 0; t0 < kchunk; t0 += ATILE) {
#pragma unroll
        for (int p = 0; p < 4; p++) {
            int slot = tid + p * 256;
            int kr = slot >> 3, e4 = slot & 7;
            const float* krow = qkv + (size_t)(kstart + t0 + kr) * (3 * D) + D + h * HD + e4 * 4;
            float4 kv = *(const float4*)krow;
            short4v ks;
            ks[0] = f2bf(kv.x); ks[1] = f2bf(kv.y); ks[2] = f2bf(kv.z); ks[3] = f2bf(kv.w);
            *(short4v*)&Ks[kr * KSTR + e4 * 4] = ks;
            const float* vrow = qkv + (size_t)(kstart + t0 + kr) * (3 * D) + 2 * D + h * HD + e4 * 4;
            float4 vv = *(const float4*)vrow;
            VTs[(e4 * 4 + 0) * VSTR + kr] = f2bf(vv.x);
            VTs[(e4 * 4 + 1) * VSTR + kr] = f2bf(vv.y);
            VTs[(e4 * 4 + 2) * VSTR + kr] = f2bf(vv.z);
            VTs[(e4 * 4 + 3) * VSTR + kr] = f2bf(vv.w);
        }
        __syncthreads();
#pragma unroll
        for (int s = 0; s < ATILE / 32; s++) {
            int sb = s * 32;
            short8 kf0 = *(const short8*)&Ks[(sb + krow0) * KSTR + quad * 8];
            short8 kf1 = *(const short8*)&Ks[(sb + krow0 + 4) * KSTR + quad * 8];
            floatx4 zero = {0.f, 0.f, 0.f, 0.f};
            floatx4 s0 = __builtin_amdgcn_mfma_f32_16x16x32_bf16(kf0, qf, zero, 0, 0, 0);
            floatx4 s1 = __builtin_amdgcn_mfma_f32_16x16x32_bf16(kf1, qf, zero, 0, 0, 0);
            float mx = fmaxf(fmaxf(fmaxf(s0[0], s0[1]), fmaxf(s0[2], s0[3])),
                             fmaxf(fmaxf(s1[0], s1[1]), fmaxf(s1[2], s1[3])));
            mx = fmaxf(mx, __shfl_xor(mx, 16));
            mx = fmaxf(mx, __shfl_xor(mx, 32));
            float nm = fmaxf(m_r, mx);
            float alpha = __expf(m_r - nm);
            float p0[4], p1[4], ls = 0.f;
#pragma unroll
            for (int j = 0; j < 4; j++) {
                p0[j] = __expf(s0[j] - nm);
                p1[j] = __expf(s1[j] - nm);
                ls += p0[j] + p1[j];
            }
            ls += __shfl_xor(ls, 16);
            ls += __shfl_xor(ls, 32);
            l_r = l_r * alpha + ls;
            m_r = nm;
            short8 pf;
#pragma unroll
            for (int j = 0; j < 4; j++) { pf[j] = f2bf(p0[j]); pf[4 + j] = f2bf(p1[j]); }
#pragma unroll
            for (int j = 0; j < 4; j++) { accA[j] *= alpha; accB[j] *= alpha; }
            short8 vf0 = *(const short8*)&VTs[mm * VSTR + sb + quad * 8];
            short8 vf1 = *(const short8*)&VTs[(mm + 16) * VSTR + sb + quad * 8];
            accA = __builtin_amdgcn_mfma_f32_16x16x32_bf16(vf0, pf, accA, 0, 0, 0);
            accB = __builtin_amdgcn_mfma_f32_16x16x32_bf16(vf1, pf, accB, 0, 0, 0);
        }
        __syncthreads();
    }
    size_t NH = (size_t)N * H;
    int qi = qbase + mm;
    size_t nh = (size_t)qi * H + h;
    if (lane < 16) {
        pm[(size_t)c * NH + nh] = m_r;
        pl[(size_t)c * NH + nh] = l_r;
    }
    float* op = po + ((size_t)c * NH + nh) * HD;
#pragma unroll
    for (int j = 0; j < 4; j++) {
        op[quad * 4 + j] = accA[j];
        op[16 + quad * 4 + j] = accB[j];
    }
}

// ---------------- combine partials -> obuf[N, 256] ----------------
__global__ __launch_bounds__(256) void attn_combine_kernel(
        const float* __restrict__ po, const float* __restrict__ pm,
        const float* __restrict__ pl, float* __restrict__ obuf, int N, int KC_) {
    int idx = blockIdx.x * 256 + threadIdx.x;
    int d = idx & (HD - 1);
    int nh = idx >> 5;
    size_t NH = (size_t)N * H;
    float M = -1e30f;
    for (int cc = 0; cc < KC_; cc++) M = fmaxf(M, pm[(size_t)cc * NH + nh]);
    float l = 0.f, o = 0.f;
    for (int cc = 0; cc < KC_; cc++) {
        float a = __expf(pm[(size_t)cc * NH + nh] - M);
        l += a * pl[(size_t)cc * NH + nh];
        o += a * po[((size_t)cc * NH + nh) * HD + d];
    }
    int n = nh >> 3, h = nh & (H - 1);
    obuf[(size_t)n * D + h * HD + d] = o / l;
}

// ---------------- launch ----------------
extern "C" void kernel_launch(void* const* d_in, const int* in_sizes, int n_in,
                              void* d_out, int out_size, void* d_ws, size_t ws_size,
                              hipStream_t stream) {
    const float* x    = (const float*)d_in[0];
    const int*   ei   = (const int*)d_in[1];
    const float* ea   = (const float*)d_in[2];
    const float* eps  = (const float*)d_in[3];
    const float* Wl   = (const float*)d_in[4];
    const float* bl   = (const float*)d_in[5];
    const float* W1   = (const float*)d_in[6];
    const float* b1   = (const float*)d_in[7];
    const float* W2   = (const float*)d_in[8];
    const float* b2   = (const float*)d_in[9];
    const float* lnlg = (const float*)d_in[10];
    const float* lnlb = (const float*)d_in[11];
    const float* in_w = (const float*)d_in[12];
    const float* in_b = (const float*)d_in[13];
    const float* outw = (const float*)d_in[14];
    const float* outb = (const float*)d_in[15];
    const float* lnag = (const float*)d_in[16];
    const float* lnab = (const float*)d_in[17];
    const float* Wf1  = (const float*)d_in[18];
    const float* bf1  = (const float*)d_in[19];
    const float* Wf2  = (const float*)d_in[20];
    const float* bf2  = (const float*)d_in[21];
    const float* lnfg = (const float*)d_in[22];
    const float* lnfb = (const float*)d_in[23];
    float* out = (float*)d_out;

    const int N = in_sizes[0] / D;       // 4096
    const int E = in_sizes[1] / 2;       // 262144
    const size_t NF = (size_t)N * D;     // 1048576
    const size_t NH = (size_t)N * H;

    const int KCsel = 4;
    size_t floatEnd = (4 + (size_t)KCsel) * NF + 2 * (size_t)KCsel * NH;
    size_t offB = (floatEnd * 4 + 15) & ~(size_t)15;
    size_t intCount = (size_t)N + 3 * (size_t)E + (size_t)(N + 1);  // cnt, perm, srcp, dstp, offs
    size_t wltOff = (offB + intCount * 4 + 15) & ~(size_t)15;

    float* w = (float*)d_ws;
    float* x1   = w;
    float* qkv  = w + NF;
    float* h    = w + 4 * NF;
    float* t1   = w + 5 * NF;
    float* t2   = w + 6 * NF;
    float* po   = w + 4 * NF;
    float* pm   = w + (4 + (size_t)KCsel) * NF;
    float* pl   = pm + (size_t)KCsel * NH;
    float* obuf = w + NF;
    float* t3   = w + 2 * NF;
    float* x2   = w + 3 * NF;
    float* f1   = w + 4 * NF;
    float* f2   = w + 6 * NF;

    char* base = (char*)d_ws;
    int* ibase  = (int*)(base + offB);
    int* cnt    = ibase;
    int* perm   = ibase + N;
    int* srcp   = perm + E;
    int* dstp   = srcp + E;
    int* offs   = dstp + E;
    short* WlT  = (short*)(base + wltOff);

    // --- edge binning ---
    zero_kernel<<<(N + 255) / 256, 256, 0, stream>>>(cnt, N);
    hist_kernel<<<(E + 255) / 256, 256, 0, stream>>>(ei, cnt, E);
    scan_kernel<<<1, 1024, 0, stream>>>(cnt, offs);
    scatter_kernel<<<(E + 255) / 256, 256, 0, stream>>>(ei, cnt, perm, srcp, dstp, E);
    wlT_kernel<<<64, 256, 0, stream>>>(Wl, WlT);
    // --- fused GINE: h = (1+eps)x + scatter-sum relu(x_src + ea@Wl + bl) ---
    init_h_kernel<<<(int)(NF / 256), 256, 0, stream>>>(x, eps, h, (int)NF);
    edge_fused_kernel<<<E / 64, 256, 0, stream>>>(ea, WlT, bl, x, perm, srcp, dstp, h);
    // --- local MLP ---
    gemm_kernel<2, false><<<dim3(D / BN, N / BM), 256, 0, stream>>>(h, W1, b1, t1, N, D, D);
    gemm_kernel<0, false><<<dim3(D / BN, N / BM), 256, 0, stream>>>(t1, W2, b2, t2, N, D, D);
    ln_res_kernel<2><<<N, 256, 0, stream>>>(t2, x, lnlg, lnlb, x1);
    // --- attention ---
    gemm_kernel<0, true><<<dim3(3 * D / BN, N / BM), 256, 0, stream>>>(x1, in_w, in_b, qkv, N, D, 3 * D);
    attn_mfma_kernel<<<dim3(N / 64, H, KCsel), 256, 0, stream>>>(qkv, po, pm, pl, N, KCsel);
    attn_combine_kernel<<<(int)(NF / 256), 256, 0, stream>>>(po, pm, pl, obuf, N, KCsel);
    gemm_kernel<0, true><<<dim3(D / BN, N / BM), 256, 0, stream>>>(obuf, outw, outb, t3, N, D, D);
    ln_res_kernel<0><<<N, 256, 0, stream>>>(t3, x1, lnag, lnab, x2);
    // --- FFN ---
    gemm_kernel<3, false><<<dim3(2 * D / BN, N / BM), 256, 0, stream>>>(x2, Wf1, bf1, f1, N, D, 2 * D);
    gemm_kernel<0, false><<<dim3(D / BN, N / BM), 256, 0, stream>>>(f1, Wf2, bf2, f2, N, 2 * D, D);
    ln_res_kernel<0><<<N, 256, 0, stream>>>(f2, x2, lnfg, lnfb, out);

    (void)n_in; (void)out_size; (void)ws_size;
}

// Round 7
// 473.528 us; speedup vs baseline: 1.4132x; 1.1502x over previous
//
#include <hip/hip_runtime.h>
#include <cstddef>

#define D 256
#define H 8
#define HD 32
#define ED 64

typedef __attribute__((ext_vector_type(8))) short short8;
typedef __attribute__((ext_vector_type(4))) short short4v;
typedef __attribute__((ext_vector_type(4))) float floatx4;

// fp32 -> bf16 RNE
__device__ inline short f2bf(float f) {
    unsigned u = __float_as_uint(f);
    unsigned r = (u + 0x7fffu + ((u >> 16) & 1u)) >> 16;
    return (short)r;
}

// ---------------- activations ----------------
template<int ACT> __device__ inline float act_f(float v) {
    if (ACT == 1) return fmaxf(v, 0.f);
    if (ACT == 2) return v > 0.f ? v : expm1f(v);              // elu
    if (ACT == 3) return 0.5f * v * (1.f + erff(v * 0.70710678118654752f)); // exact gelu
    return v;
}

__device__ inline float wave_sum(float v) {
#pragma unroll
    for (int off = 32; off > 0; off >>= 1) v += __shfl_xor(v, off, 64);
    return v;
}

// ================= edge binning pipeline =================
__global__ void zero_kernel(int* __restrict__ p, int n) {
    int i = blockIdx.x * 256 + threadIdx.x;
    if (i < n) p[i] = 0;
}

__global__ void hist_kernel(const int* __restrict__ ei, int* __restrict__ cnt, int E) {
    int e = blockIdx.x * 256 + threadIdx.x;
    if (e < E) atomicAdd(&cnt[ei[E + e]], 1);
}

__global__ __launch_bounds__(1024) void scan_kernel(int* __restrict__ cnt,
                                                    int* __restrict__ offs) {
    __shared__ int s[1024];
    int tid = threadIdx.x;
    int4 c = *(int4*)&cnt[tid * 4];
    int sum = c.x + c.y + c.z + c.w;
    s[tid] = sum;
    __syncthreads();
    for (int off = 1; off < 1024; off <<= 1) {
        int v = (tid >= off) ? s[tid - off] : 0;
        __syncthreads();
        s[tid] += v;
        __syncthreads();
    }
    int ex = s[tid] - sum;
    int o1 = ex + c.x, o2 = o1 + c.y, o3 = o2 + c.z;
    offs[tid * 4] = ex; offs[tid * 4 + 1] = o1;
    offs[tid * 4 + 2] = o2; offs[tid * 4 + 3] = o3;
    cnt[tid * 4] = ex; cnt[tid * 4 + 1] = o1;
    cnt[tid * 4 + 2] = o2; cnt[tid * 4 + 3] = o3;
    if (tid == 1023) offs[4096] = s[1023];
}

__global__ void scatter_kernel(const int* __restrict__ ei, int* __restrict__ cursor,
                               int* __restrict__ perm, int* __restrict__ srcp,
                               int* __restrict__ dstp, int E) {
    int e = blockIdx.x * 256 + threadIdx.x;
    if (e < E) {
        int d = ei[E + e];
        int pos = atomicAdd(&cursor[d], 1);
        perm[pos] = e;
        srcp[pos] = ei[e];
        dstp[pos] = d;
    }
}

// Wl [64][256] fp32 -> WlT [256][64] bf16
__global__ void wlT_kernel(const float* __restrict__ Wl, short* __restrict__ WlT) {
    int idx = blockIdx.x * 256 + threadIdx.x;   // 16384
    int n = idx >> 6, k = idx & 63;
    WlT[idx] = f2bf(Wl[k * D + n]);
}

// fp32 [K][Nc] -> bf16 [Nc][K] (transpose)
__global__ void convt_kernel(const float* __restrict__ in, short* __restrict__ o,
                             int K, int Nc) {
    int idx = blockIdx.x * 256 + threadIdx.x;
    if (idx < K * Nc) {
        int n = idx / K, k = idx - n * K;
        o[idx] = f2bf(in[k * Nc + n]);
    }
}
// fp32 [N][K] -> bf16 [N][K] (straight)
__global__ void conv_kernel(const float* __restrict__ in, short* __restrict__ o, int total) {
    int idx = blockIdx.x * 256 + threadIdx.x;
    if (idx < total) o[idx] = f2bf(in[idx]);
}

// h = (1+eps)*x
__global__ void init_h_kernel(const float* __restrict__ x, const float* __restrict__ eps,
                              float* __restrict__ h, int total) {
    int i = blockIdx.x * 256 + threadIdx.x;
    if (i < total) h[i] = (1.f + eps[0]) * x[i];
}

// Fused GINE edge kernel (MFMA edge-linear + gather + relu + segment scatter)
__global__ __launch_bounds__(256) void edge_fused_kernel(
        const float* __restrict__ ea, const short* __restrict__ WlT,
        const float* __restrict__ bl, const float* __restrict__ x,
        const int* __restrict__ perm, const int* __restrict__ srcp,
        const int* __restrict__ dstp, float* __restrict__ h) {
    __shared__ __align__(16) short ea_s[64 * 72];
    __shared__ int s_src[64], s_dst[64];
    int tid = threadIdx.x;
    int wave = tid >> 6, lane = tid & 63;
    int mm = lane & 15, quad = lane >> 4;
    int e0 = blockIdx.x * 64;
    if (tid < 64) {
        s_src[tid] = srcp[e0 + tid];
        s_dst[tid] = dstp[e0 + tid];
    }
    {
        __shared__ int s_perm[64];
        if (tid >= 64 && tid < 128) s_perm[tid - 64] = perm[e0 + tid - 64];
        __syncthreads();
#pragma unroll
        for (int p = 0; p < 4; p++) {
            int slot = tid + p * 256;
            int row = slot >> 4, c4 = slot & 15;
            float4 v = *(const float4*)&ea[(size_t)s_perm[row] * ED + c4 * 4];
            short4v s; s[0] = f2bf(v.x); s[1] = f2bf(v.y); s[2] = f2bf(v.z); s[3] = f2bf(v.w);
            *(short4v*)&ea_s[row * 72 + c4 * 4] = s;
        }
    }
    __syncthreads();
    short8 af[4][2];
#pragma unroll
    for (int t = 0; t < 4; t++)
#pragma unroll
        for (int q2 = 0; q2 < 2; q2++)
            af[t][q2] = *(const short8*)&WlT[(wave * 64 + t * 16 + mm) * 64 + q2 * 32 + quad * 8];
    floatx4 acc[4][4];
#pragma unroll
    for (int et = 0; et < 4; et++)
#pragma unroll
        for (int t = 0; t < 4; t++) acc[et][t] = (floatx4){0.f, 0.f, 0.f, 0.f};
#pragma unroll
    for (int et = 0; et < 4; et++) {
        short8 bf0 = *(const short8*)&ea_s[(et * 16 + mm) * 72 + quad * 8];
        short8 bf1 = *(const short8*)&ea_s[(et * 16 + mm) * 72 + 32 + quad * 8];
#pragma unroll
        for (int t = 0; t < 4; t++) {
            acc[et][t] = __builtin_amdgcn_mfma_f32_16x16x32_bf16(af[t][0], bf0, acc[et][t], 0, 0, 0);
            acc[et][t] = __builtin_amdgcn_mfma_f32_16x16x32_bf16(af[t][1], bf1, acc[et][t], 0, 0, 0);
        }
    }
    float4 blv[4];
#pragma unroll
    for (int t = 0; t < 4; t++)
        blv[t] = *(const float4*)&bl[wave * 64 + t * 16 + quad * 4];
#pragma unroll
    for (int et = 0; et < 4; et++) {
        const float* xrow = x + (size_t)s_src[et * 16 + mm] * D + wave * 64 + quad * 4;
#pragma unroll
        for (int t = 0; t < 4; t++) {
            float4 xv = *(const float4*)(xrow + t * 16);
            acc[et][t][0] = fmaxf(acc[et][t][0] + blv[t].x + xv.x, 0.f);
            acc[et][t][1] = fmaxf(acc[et][t][1] + blv[t].y + xv.y, 0.f);
            acc[et][t][2] = fmaxf(acc[et][t][2] + blv[t].z + xv.z, 0.f);
            acc[et][t][3] = fmaxf(acc[et][t][3] + blv[t].w + xv.w, 0.f);
        }
    }
    int segstart = 0;
    while (segstart < 64) {
        int segdst = s_dst[segstart];
        int segend = segstart + 1;
        while (segend < 64 && s_dst[segend] == segdst) segend++;
        bool in0 = (0 * 16 + mm >= segstart) & (0 * 16 + mm < segend);
        bool in1 = (1 * 16 + mm >= segstart) & (1 * 16 + mm < segend);
        bool in2 = (2 * 16 + mm >= segstart) & (2 * 16 + mm < segend);
        bool in3 = (3 * 16 + mm >= segstart) & (3 * 16 + mm < segend);
        float* hrow = h + (size_t)segdst * D + wave * 64;
#pragma unroll
        for (int t = 0; t < 4; t++) {
#pragma unroll
            for (int j = 0; j < 4; j++) {
                float v = (in0 ? acc[0][t][j] : 0.f) + (in1 ? acc[1][t][j] : 0.f)
                        + (in2 ? acc[2][t][j] : 0.f) + (in3 ? acc[3][t][j] : 0.f);
                v += __shfl_xor(v, 1);
                v += __shfl_xor(v, 2);
                v += __shfl_xor(v, 4);
                v += __shfl_xor(v, 8);
                if (mm == 0) atomicAdd(&hrow[t * 16 + quad * 4 + j], v);
            }
        }
        segstart = segend;
    }
}

// ---------------- bf16 MFMA GEMM: C[M,Nc] = act(A[M,K] @ Bt^T + bias) ----------------
// A fp32 row-major [M][K] (converted on the fly); Bt bf16 [Nc][K]; C fp32 [M][Nc].
// 64x64 tile, 4 waves in 2x2 grid, each wave 2x2 MFMA 16x16x32 tiles.
#define GSTR 40
template<int ACT>
__global__ __launch_bounds__(256) void gemm_bf16_kernel(
        const float* __restrict__ A, const short* __restrict__ Bt,
        const float* __restrict__ bias, float* __restrict__ C,
        int M, int K, int Nc) {
    __shared__ __align__(16) short As[64 * GSTR];
    __shared__ __align__(16) short Bs[64 * GSTR];
    int tid = threadIdx.x;
    int wave = tid >> 6, lane = tid & 63;
    int mm = lane & 15, quad = lane >> 4;
    int wm = wave >> 1, wn = wave & 1;
    int m0 = blockIdx.y * 64, n0 = blockIdx.x * 64;
    floatx4 acc[2][2];
#pragma unroll
    for (int i = 0; i < 2; i++)
#pragma unroll
        for (int j = 0; j < 2; j++) acc[i][j] = (floatx4){0.f, 0.f, 0.f, 0.f};
    for (int k0 = 0; k0 < K; k0 += 32) {
        // A: 64 rows x 32 cols fp32 -> bf16 (512 float4 slots, 2/thread)
#pragma unroll
        for (int p = 0; p < 2; p++) {
            int slot = tid + p * 256;
            int row = slot >> 3, c4 = slot & 7;
            float4 v = *(const float4*)&A[(size_t)(m0 + row) * K + k0 + c4 * 4];
            short4v s; s[0] = f2bf(v.x); s[1] = f2bf(v.y); s[2] = f2bf(v.z); s[3] = f2bf(v.w);
            *(short4v*)&As[row * GSTR + c4 * 4] = s;
        }
        // B: 64 rows x 32 cols bf16 (256 ushort8 slots, 1/thread)
        {
            int row = tid >> 2, seg = tid & 3;
            short8 v = *(const short8*)&Bt[(size_t)(n0 + row) * K + k0 + seg * 8];
            *(short8*)&Bs[row * GSTR + seg * 8] = v;
        }
        __syncthreads();
        short8 af[2], bf[2];
#pragma unroll
        for (int t = 0; t < 2; t++) {
            af[t] = *(const short8*)&As[(wm * 32 + t * 16 + mm) * GSTR + quad * 8];
            bf[t] = *(const short8*)&Bs[(wn * 32 + t * 16 + mm) * GSTR + quad * 8];
        }
#pragma unroll
        for (int i = 0; i < 2; i++)
#pragma unroll
            for (int j = 0; j < 2; j++)
                acc[i][j] = __builtin_amdgcn_mfma_f32_16x16x32_bf16(af[i], bf[j], acc[i][j], 0, 0, 0);
        __syncthreads();
    }
    // epilogue: C[m = m0+wm*32+i*16+quad*4+r][n = n0+wn*32+j*16+mm]
#pragma unroll
    for (int i = 0; i < 2; i++) {
#pragma unroll
        for (int j = 0; j < 2; j++) {
            int ncol = n0 + wn * 32 + j * 16 + mm;
            float bv = bias[ncol];
#pragma unroll
            for (int r = 0; r < 4; r++) {
                int mrow = m0 + wm * 32 + i * 16 + quad * 4 + r;
                C[(size_t)mrow * Nc + ncol] = act_f<ACT>(acc[i][j][r] + bv);
            }
        }
    }
}

// ---------------- row LayerNorm + optional ELU + residual ----------------
template<int ACT>
__global__ __launch_bounds__(256) void ln_res_kernel(
        const float* __restrict__ t, const float* __restrict__ res,
        const float* __restrict__ g, const float* __restrict__ b,
        float* __restrict__ out) {
    __shared__ float red[8];
    int row = blockIdx.x, tid = threadIdx.x;
    float v = t[(size_t)row * D + tid];
    int wid = tid >> 6, lane = tid & 63;
    float s = wave_sum(v);
    if (lane == 0) red[wid] = s;
    __syncthreads();
    float mu = (red[0] + red[1] + red[2] + red[3]) * (1.f / D);
    float dv = v - mu;
    float s2 = wave_sum(dv * dv);
    if (lane == 0) red[4 + wid] = s2;
    __syncthreads();
    float var = (red[4] + red[5] + red[6] + red[7]) * (1.f / D);
    float y = dv * rsqrtf(var + 1e-5f) * g[tid] + b[tid];
    y = act_f<ACT>(y);
    out[(size_t)row * D + tid] = res[(size_t)row * D + tid] + y;
}

// ---------------- MFMA flash attention (split-K partials) ----------------
#define KSTR 40
#define VSTR 136
#define ATILE 128
__global__ __launch_bounds__(256) void attn_mfma_kernel(
        const float* __restrict__ qkv, float* __restrict__ po,
        float* __restrict__ pm, float* __restrict__ pl, int N, int KC_) {
    __shared__ __align__(16) short Ks[ATILE * KSTR];
    __shared__ __align__(16) short VTs[HD * VSTR];
    const int tid = threadIdx.x;
    const int wave = tid >> 6, lane = tid & 63;
    const int mm = lane & 15, quad = lane >> 4;
    const int h = blockIdx.y, c = blockIdx.z;
    const int qbase = blockIdx.x * 64 + wave * 16;
    const float scale = 0.17677669529663687f; // 1/sqrt(32)

    short8 qf;
    {
        const float* qrow = qkv + (size_t)(qbase + mm) * (3 * D) + h * HD + quad * 8;
        float4 a = *(const float4*)qrow;
        float4 b = *(const float4*)(qrow + 4);
        qf[0] = f2bf(a.x * scale); qf[1] = f2bf(a.y * scale);
        qf[2] = f2bf(a.z * scale); qf[3] = f2bf(a.w * scale);
        qf[4] = f2bf(b.x * scale); qf[5] = f2bf(b.y * scale);
        qf[6] = f2bf(b.z * scale); qf[7] = f2bf(b.w * scale);
    }
    floatx4 accA = {0.f, 0.f, 0.f, 0.f};
    floatx4 accB = {0.f, 0.f, 0.f, 0.f};
    float m_r = -1e30f, l_r = 0.f;

    const int kchunk = N / KC_;
    const int kstart = c * kchunk;
    const int krow0 = ((mm >> 2) << 3) | (mm & 3);

    for (int t0 = 0; t0 < kchunk; t0 += ATILE) {
#pragma unroll
        for (int p = 0; p < 4; p++) {
            int slot = tid + p * 256;
            int kr = slot >> 3, e4 = slot & 7;
            const float* krow = qkv + (size_t)(kstart + t0 + kr) * (3 * D) + D + h * HD + e4 * 4;
            float4 kv = *(const float4*)krow;
            short4v ks;
            ks[0] = f2bf(kv.x); ks[1] = f2bf(kv.y); ks[2] = f2bf(kv.z); ks[3] = f2bf(kv.w);
            *(short4v*)&Ks[kr * KSTR + e4 * 4] = ks;
            const float* vrow = qkv + (size_t)(kstart + t0 + kr) * (3 * D) + 2 * D + h * HD + e4 * 4;
            float4 vv = *(const float4*)vrow;
            VTs[(e4 * 4 + 0) * VSTR + kr] = f2bf(vv.x);
            VTs[(e4 * 4 + 1) * VSTR + kr] = f2bf(vv.y);
            VTs[(e4 * 4 + 2) * VSTR + kr] = f2bf(vv.z);
            VTs[(e4 * 4 + 3) * VSTR + kr] = f2bf(vv.w);
        }
        __syncthreads();
#pragma unroll
        for (int s = 0; s < ATILE / 32; s++) {
            int sb = s * 32;
            short8 kf0 = *(const short8*)&Ks[(sb + krow0) * KSTR + quad * 8];
            short8 kf1 = *(const short8*)&Ks[(sb + krow0 + 4) * KSTR + quad * 8];
            floatx4 zero = {0.f, 0.f, 0.f, 0.f};
            floatx4 s0 = __builtin_amdgcn_mfma_f32_16x16x32_bf16(kf0, qf, zero, 0, 0, 0);
            floatx4 s1 = __builtin_amdgcn_mfma_f32_16x16x32_bf16(kf1, qf, zero, 0, 0, 0);
            float mx = fmaxf(fmaxf(fmaxf(s0[0], s0[1]), fmaxf(s0[2], s0[3])),
                             fmaxf(fmaxf(s1[0], s1[1]), fmaxf(s1[2], s1[3])));
            mx = fmaxf(mx, __shfl_xor(mx, 16));
            mx = fmaxf(mx, __shfl_xor(mx, 32));
            float nm = fmaxf(m_r, mx);
            float alpha = __expf(m_r - nm);
            float p0[4], p1[4], ls = 0.f;
#pragma unroll
            for (int j = 0; j < 4; j++) {
                p0[j] = __expf(s0[j] - nm);
                p1[j] = __expf(s1[j] - nm);
                ls += p0[j] + p1[j];
            }
            ls += __shfl_xor(ls, 16);
            ls += __shfl_xor(ls, 32);
            l_r = l_r * alpha + ls;
            m_r = nm;
            short8 pf;
#pragma unroll
            for (int j = 0; j < 4; j++) { pf[j] = f2bf(p0[j]); pf[4 + j] = f2bf(p1[j]); }
#pragma unroll
            for (int j = 0; j < 4; j++) { accA[j] *= alpha; accB[j] *= alpha; }
            short8 vf0 = *(const short8*)&VTs[mm * VSTR + sb + quad * 8];
            short8 vf1 = *(const short8*)&VTs[(mm + 16) * VSTR + sb + quad * 8];
            accA = __builtin_amdgcn_mfma_f32_16x16x32_bf16(vf0, pf, accA, 0, 0, 0);
            accB = __builtin_amdgcn_mfma_f32_16x16x32_bf16(vf1, pf, accB, 0, 0, 0);
        }
        __syncthreads();
    }
    size_t NH = (size_t)N * H;
    int qi = qbase + mm;
    size_t nh = (size_t)qi * H + h;
    if (lane < 16) {
        pm[(size_t)c * NH + nh] = m_r;
        pl[(size_t)c * NH + nh] = l_r;
    }
    float* op = po + ((size_t)c * NH + nh) * HD;
#pragma unroll
    for (int j = 0; j < 4; j++) {
        op[quad * 4 + j] = accA[j];
        op[16 + quad * 4 + j] = accB[j];
    }
}

// ---------------- combine partials -> obuf[N, 256] ----------------
__global__ __launch_bounds__(256) void attn_combine_kernel(
        const float* __restrict__ po, const float* __restrict__ pm,
        const float* __restrict__ pl, float* __restrict__ obuf, int N, int KC_) {
    int idx = blockIdx.x * 256 + threadIdx.x;
    int d = idx & (HD - 1);
    int nh = idx >> 5;
    size_t NH = (size_t)N * H;
    float M = -1e30f;
    for (int cc = 0; cc < KC_; cc++) M = fmaxf(M, pm[(size_t)cc * NH + nh]);
    float l = 0.f, o = 0.f;
    for (int cc = 0; cc < KC_; cc++) {
        float a = __expf(pm[(size_t)cc * NH + nh] - M);
        l += a * pl[(size_t)cc * NH + nh];
        o += a * po[((size_t)cc * NH + nh) * HD + d];
    }
    int n = nh >> 3, h = nh & (H - 1);
    obuf[(size_t)n * D + h * HD + d] = o / l;
}

// ---------------- launch ----------------
extern "C" void kernel_launch(void* const* d_in, const int* in_sizes, int n_in,
                              void* d_out, int out_size, void* d_ws, size_t ws_size,
                              hipStream_t stream) {
    const float* x    = (const float*)d_in[0];
    const int*   ei   = (const int*)d_in[1];
    const float* ea   = (const float*)d_in[2];
    const float* eps  = (const float*)d_in[3];
    const float* Wl   = (const float*)d_in[4];
    const float* bl   = (const float*)d_in[5];
    const float* W1   = (const float*)d_in[6];
    const float* b1   = (const float*)d_in[7];
    const float* W2   = (const float*)d_in[8];
    const float* b2   = (const float*)d_in[9];
    const float* lnlg = (const float*)d_in[10];
    const float* lnlb = (const float*)d_in[11];
    const float* in_w = (const float*)d_in[12];
    const float* in_b = (const float*)d_in[13];
    const float* outw = (const float*)d_in[14];
    const float* outb = (const float*)d_in[15];
    const float* lnag = (const float*)d_in[16];
    const float* lnab = (const float*)d_in[17];
    const float* Wf1  = (const float*)d_in[18];
    const float* bf1  = (const float*)d_in[19];
    const float* Wf2  = (const float*)d_in[20];
    const float* bf2  = (const float*)d_in[21];
    const float* lnfg = (const float*)d_in[22];
    const float* lnfb = (const float*)d_in[23];
    float* out = (float*)d_out;

    const int N = in_sizes[0] / D;       // 4096
    const int E = in_sizes[1] / 2;       // 262144
    const size_t NF = (size_t)N * D;     // 1048576
    const size_t NH = (size_t)N * H;

    const int KCsel = 4;
    size_t floatEnd = (4 + (size_t)KCsel) * NF + 2 * (size_t)KCsel * NH;
    size_t offB = (floatEnd * 4 + 15) & ~(size_t)15;
    size_t intCount = (size_t)N + 3 * (size_t)E + (size_t)(N + 1);  // cnt, perm, srcp, dstp, offs
    size_t wltOff = (offB + intCount * 4 + 15) & ~(size_t)15;

    float* w = (float*)d_ws;
    float* x1   = w;
    float* qkv  = w + NF;
    float* h    = w + 4 * NF;
    float* t1   = w + 5 * NF;
    float* t2   = w + 6 * NF;
    float* po   = w + 4 * NF;
    float* pm   = w + (4 + (size_t)KCsel) * NF;
    float* pl   = pm + (size_t)KCsel * NH;
    float* obuf = w + NF;
    float* t3   = w + 2 * NF;
    float* x2   = w + 3 * NF;
    float* f1   = w + 4 * NF;
    float* f2   = w + 6 * NF;

    char* base = (char*)d_ws;
    int* ibase  = (int*)(base + offB);
    int* cnt    = ibase;
    int* perm   = ibase + N;
    int* srcp   = perm + E;
    int* dstp   = srcp + E;
    int* offs   = dstp + E;
    short* WlT    = (short*)(base + wltOff);   // 16384
    short* W1bt   = WlT + 16384;               // [256][256]
    short* W2bt   = W1bt + 65536;
    short* inwbt  = W2bt + 65536;              // [768][256]
    short* outwbt = inwbt + 196608;            // [256][256]
    short* Wf1bt  = outwbt + 65536;            // [512][256]
    short* Wf2bt  = Wf1bt + 131072;            // [256][512]

    // --- weight conversions (bf16, [N][K] layout) ---
    wlT_kernel<<<64, 256, 0, stream>>>(Wl, WlT);
    convt_kernel<<<256, 256, 0, stream>>>(W1, W1bt, 256, 256);
    convt_kernel<<<256, 256, 0, stream>>>(W2, W2bt, 256, 256);
    conv_kernel<<<768, 256, 0, stream>>>(in_w, inwbt, 196608);
    conv_kernel<<<256, 256, 0, stream>>>(outw, outwbt, 65536);
    convt_kernel<<<512, 256, 0, stream>>>(Wf1, Wf1bt, 256, 512);
    convt_kernel<<<512, 256, 0, stream>>>(Wf2, Wf2bt, 512, 256);

    // --- edge binning ---
    zero_kernel<<<(N + 255) / 256, 256, 0, stream>>>(cnt, N);
    hist_kernel<<<(E + 255) / 256, 256, 0, stream>>>(ei, cnt, E);
    scan_kernel<<<1, 1024, 0, stream>>>(cnt, offs);
    scatter_kernel<<<(E + 255) / 256, 256, 0, stream>>>(ei, cnt, perm, srcp, dstp, E);
    // --- fused GINE ---
    init_h_kernel<<<(int)(NF / 256), 256, 0, stream>>>(x, eps, h, (int)NF);
    edge_fused_kernel<<<E / 64, 256, 0, stream>>>(ea, WlT, bl, x, perm, srcp, dstp, h);
    // --- local MLP ---
    gemm_bf16_kernel<2><<<dim3(D / 64, N / 64), 256, 0, stream>>>(h, W1bt, b1, t1, N, D, D);
    gemm_bf16_kernel<0><<<dim3(D / 64, N / 64), 256, 0, stream>>>(t1, W2bt, b2, t2, N, D, D);
    ln_res_kernel<2><<<N, 256, 0, stream>>>(t2, x, lnlg, lnlb, x1);
    // --- attention ---
    gemm_bf16_kernel<0><<<dim3(3 * D / 64, N / 64), 256, 0, stream>>>(x1, inwbt, in_b, qkv, N, D, 3 * D);
    attn_mfma_kernel<<<dim3(N / 64, H, KCsel), 256, 0, stream>>>(qkv, po, pm, pl, N, KCsel);
    attn_combine_kernel<<<(int)(NF / 256), 256, 0, stream>>>(po, pm, pl, obuf, N, KCsel);
    gemm_bf16_kernel<0><<<dim3(D / 64, N / 64), 256, 0, stream>>>(obuf, outwbt, outb, t3, N, D, D);
    ln_res_kernel<0><<<N, 256, 0, stream>>>(t3, x1, lnag, lnab, x2);
    // --- FFN ---
    gemm_bf16_kernel<3><<<dim3(2 * D / 64, N / 64), 256, 0, stream>>>(x2, Wf1bt, bf1, f1, N, D, 2 * D);
    gemm_bf16_kernel<0><<<dim3(D / 64, N / 64), 256, 0, stream>>>(f1, Wf2bt, bf2, f2, N, 2 * D, D);
    ln_res_kernel<0><<<N, 256, 0, stream>>>(f2, x2, lnfg, lnfb, out);

    (void)n_in; (void)out_size; (void)ws_size;
}

// Round 8
// 455.759 us; speedup vs baseline: 1.4683x; 1.0390x over previous
//
#include <hip/hip_runtime.h>
#include <cstddef>

#define D 256
#define H 8
#define HD 32
#define ED 64

typedef __attribute__((ext_vector_type(8))) short short8;
typedef __attribute__((ext_vector_type(4))) short short4v;
typedef __attribute__((ext_vector_type(4))) float floatx4;

// fp32 -> bf16 RNE
__device__ inline short f2bf(float f) {
    unsigned u = __float_as_uint(f);
    unsigned r = (u + 0x7fffu + ((u >> 16) & 1u)) >> 16;
    return (short)r;
}

// ---------------- activations ----------------
template<int ACT> __device__ inline float act_f(float v) {
    if (ACT == 1) return fmaxf(v, 0.f);
    if (ACT == 2) return v > 0.f ? v : expm1f(v);              // elu
    if (ACT == 3) return 0.5f * v * (1.f + erff(v * 0.70710678118654752f)); // exact gelu
    return v;
}

__device__ inline float wave_sum(float v) {
#pragma unroll
    for (int off = 32; off > 0; off >>= 1) v += __shfl_xor(v, off, 64);
    return v;
}

// ================= edge binning pipeline =================
__global__ void zero_kernel(int* __restrict__ p, int n) {
    int i = blockIdx.x * 256 + threadIdx.x;
    if (i < n) p[i] = 0;
}

__global__ void hist_kernel(const int* __restrict__ ei, int* __restrict__ cnt, int E) {
    int e = blockIdx.x * 256 + threadIdx.x;
    if (e < E) atomicAdd(&cnt[ei[E + e]], 1);
}

__global__ __launch_bounds__(1024) void scan_kernel(int* __restrict__ cnt,
                                                    int* __restrict__ offs) {
    __shared__ int s[1024];
    int tid = threadIdx.x;
    int4 c = *(int4*)&cnt[tid * 4];
    int sum = c.x + c.y + c.z + c.w;
    s[tid] = sum;
    __syncthreads();
    for (int off = 1; off < 1024; off <<= 1) {
        int v = (tid >= off) ? s[tid - off] : 0;
        __syncthreads();
        s[tid] += v;
        __syncthreads();
    }
    int ex = s[tid] - sum;
    int o1 = ex + c.x, o2 = o1 + c.y, o3 = o2 + c.z;
    offs[tid * 4] = ex; offs[tid * 4 + 1] = o1;
    offs[tid * 4 + 2] = o2; offs[tid * 4 + 3] = o3;
    cnt[tid * 4] = ex; cnt[tid * 4 + 1] = o1;
    cnt[tid * 4 + 2] = o2; cnt[tid * 4 + 3] = o3;
    if (tid == 1023) offs[4096] = s[1023];
}

__global__ void scatter_kernel(const int* __restrict__ ei, int* __restrict__ cursor,
                               int* __restrict__ perm, int* __restrict__ srcp,
                               int* __restrict__ dstp, int E) {
    int e = blockIdx.x * 256 + threadIdx.x;
    if (e < E) {
        int d = ei[E + e];
        int pos = atomicAdd(&cursor[d], 1);
        perm[pos] = e;
        srcp[pos] = ei[e];
        dstp[pos] = d;
    }
}

// Wl [64][256] fp32 -> WlT [256][64] bf16
__global__ void wlT_kernel(const float* __restrict__ Wl, short* __restrict__ WlT) {
    int idx = blockIdx.x * 256 + threadIdx.x;   // 16384
    int n = idx >> 6, k = idx & 63;
    WlT[idx] = f2bf(Wl[k * D + n]);
}

// fp32 [K][Nc] -> bf16 [Nc][K] (transpose)
__global__ void convt_kernel(const float* __restrict__ in, short* __restrict__ o,
                             int K, int Nc) {
    int idx = blockIdx.x * 256 + threadIdx.x;
    if (idx < K * Nc) {
        int n = idx / K, k = idx - n * K;
        o[idx] = f2bf(in[k * Nc + n]);
    }
}
// fp32 [N][K] -> bf16 [N][K] (straight)
__global__ void conv_kernel(const float* __restrict__ in, short* __restrict__ o, int total) {
    int idx = blockIdx.x * 256 + threadIdx.x;
    if (idx < total) o[idx] = f2bf(in[idx]);
}

// h = (1+eps)*x
__global__ void init_h_kernel(const float* __restrict__ x, const float* __restrict__ eps,
                              float* __restrict__ h, int total) {
    int i = blockIdx.x * 256 + threadIdx.x;
    if (i < total) h[i] = (1.f + eps[0]) * x[i];
}

// Fused GINE edge kernel. Per block: 64 permuted edges (sorted by dst).
// MFMA edge-linear + bias + x[src] gather + relu in registers, then
// ballot-based parallel segmentation (no serial LDS walk) + shuffle
// reduction + atomicAdd spill into h.
__global__ __launch_bounds__(256) void edge_fused_kernel(
        const float* __restrict__ ea, const short* __restrict__ WlT,
        const float* __restrict__ bl, const float* __restrict__ x,
        const int* __restrict__ perm, const int* __restrict__ srcp,
        const int* __restrict__ dstp, float* __restrict__ h) {
    __shared__ __align__(16) short ea_s[64 * 72];
    int tid = threadIdx.x;
    int wave = tid >> 6, lane = tid & 63;
    int mm = lane & 15, quad = lane >> 4;
    int e0 = blockIdx.x * 64;
    // per-lane metadata in registers (each wave loads all 64; coalesced, L2-hot)
    int myperm = perm[e0 + lane];
    int mysrc  = srcp[e0 + lane];
    int mydst  = dstp[e0 + lane];
    // stage ea rows (permuted) as bf16 B-operand; row's perm via shuffle
#pragma unroll
    for (int p = 0; p < 4; p++) {
        int slot = tid + p * 256;          // 0..1023
        int row = slot >> 4, c4 = slot & 15;
        int prow = __shfl(myperm, row);
        float4 v = *(const float4*)&ea[(size_t)prow * ED + c4 * 4];
        short4v s; s[0] = f2bf(v.x); s[1] = f2bf(v.y); s[2] = f2bf(v.z); s[3] = f2bf(v.w);
        *(short4v*)&ea_s[row * 72 + c4 * 4] = s;
    }
    __syncthreads();
    // A fragments: WlT rows = output col (this wave covers cols wave*64..+64)
    short8 af[4][2];
#pragma unroll
    for (int t = 0; t < 4; t++)
#pragma unroll
        for (int q2 = 0; q2 < 2; q2++)
            af[t][q2] = *(const short8*)&WlT[(wave * 64 + t * 16 + mm) * 64 + q2 * 32 + quad * 8];
    floatx4 acc[4][4];
#pragma unroll
    for (int et = 0; et < 4; et++)
#pragma unroll
        for (int t = 0; t < 4; t++) acc[et][t] = (floatx4){0.f, 0.f, 0.f, 0.f};
#pragma unroll
    for (int et = 0; et < 4; et++) {
        short8 bf0 = *(const short8*)&ea_s[(et * 16 + mm) * 72 + quad * 8];
        short8 bf1 = *(const short8*)&ea_s[(et * 16 + mm) * 72 + 32 + quad * 8];
#pragma unroll
        for (int t = 0; t < 4; t++) {
            acc[et][t] = __builtin_amdgcn_mfma_f32_16x16x32_bf16(af[t][0], bf0, acc[et][t], 0, 0, 0);
            acc[et][t] = __builtin_amdgcn_mfma_f32_16x16x32_bf16(af[t][1], bf1, acc[et][t], 0, 0, 0);
        }
    }
    float4 blv[4];
#pragma unroll
    for (int t = 0; t < 4; t++)
        blv[t] = *(const float4*)&bl[wave * 64 + t * 16 + quad * 4];
    // + x[src] gather, relu  (lane: edge et*16+mm, cols wave*64+t*16+quad*4+j)
#pragma unroll
    for (int et = 0; et < 4; et++) {
        int srci = __shfl(mysrc, et * 16 + mm);
        const float* xrow = x + (size_t)srci * D + wave * 64 + quad * 4;
#pragma unroll
        for (int t = 0; t < 4; t++) {
            float4 xv = *(const float4*)(xrow + t * 16);
            acc[et][t][0] = fmaxf(acc[et][t][0] + blv[t].x + xv.x, 0.f);
            acc[et][t][1] = fmaxf(acc[et][t][1] + blv[t].y + xv.y, 0.f);
            acc[et][t][2] = fmaxf(acc[et][t][2] + blv[t].z + xv.z, 0.f);
            acc[et][t][3] = fmaxf(acc[et][t][3] + blv[t].w + xv.w, 0.f);
        }
    }
    // parallel segmentation: boundary where dst changes (bit0 always set)
    int prevd = __shfl_up(mydst, 1);
    bool bnd = (lane == 0) || (mydst != prevd);
    unsigned long long bmask = __ballot(bnd);
    unsigned long long m = bmask;
    while (m) {
        int segstart = (int)__builtin_ctzll(m);
        m &= m - 1;
        int segend = m ? (int)__builtin_ctzll(m) : 64;
        int segdst = __shfl(mydst, segstart);
        bool in0 = (0 * 16 + mm >= segstart) & (0 * 16 + mm < segend);
        bool in1 = (1 * 16 + mm >= segstart) & (1 * 16 + mm < segend);
        bool in2 = (2 * 16 + mm >= segstart) & (2 * 16 + mm < segend);
        bool in3 = (3 * 16 + mm >= segstart) & (3 * 16 + mm < segend);
        float* hrow = h + (size_t)segdst * D + wave * 64;
#pragma unroll
        for (int t = 0; t < 4; t++) {
#pragma unroll
            for (int j = 0; j < 4; j++) {
                float v = (in0 ? acc[0][t][j] : 0.f) + (in1 ? acc[1][t][j] : 0.f)
                        + (in2 ? acc[2][t][j] : 0.f) + (in3 ? acc[3][t][j] : 0.f);
                v += __shfl_xor(v, 1);
                v += __shfl_xor(v, 2);
                v += __shfl_xor(v, 4);
                v += __shfl_xor(v, 8);
                if (mm == 0) atomicAdd(&hrow[t * 16 + quad * 4 + j], v);
            }
        }
    }
}

// ---------------- bf16 MFMA GEMM: C[M,Nc] = act(A[M,K] @ Bt^T + bias) ----------------
#define GSTR 40
template<int ACT>
__global__ __launch_bounds__(256) void gemm_bf16_kernel(
        const float* __restrict__ A, const short* __restrict__ Bt,
        const float* __restrict__ bias, float* __restrict__ C,
        int M, int K, int Nc) {
    __shared__ __align__(16) short As[64 * GSTR];
    __shared__ __align__(16) short Bs[64 * GSTR];
    int tid = threadIdx.x;
    int wave = tid >> 6, lane = tid & 63;
    int mm = lane & 15, quad = lane >> 4;
    int wm = wave >> 1, wn = wave & 1;
    int m0 = blockIdx.y * 64, n0 = blockIdx.x * 64;
    floatx4 acc[2][2];
#pragma unroll
    for (int i = 0; i < 2; i++)
#pragma unroll
        for (int j = 0; j < 2; j++) acc[i][j] = (floatx4){0.f, 0.f, 0.f, 0.f};
    for (int k0 = 0; k0 < K; k0 += 32) {
#pragma unroll
        for (int p = 0; p < 2; p++) {
            int slot = tid + p * 256;
            int row = slot >> 3, c4 = slot & 7;
            float4 v = *(const float4*)&A[(size_t)(m0 + row) * K + k0 + c4 * 4];
            short4v s; s[0] = f2bf(v.x); s[1] = f2bf(v.y); s[2] = f2bf(v.z); s[3] = f2bf(v.w);
            *(short4v*)&As[row * GSTR + c4 * 4] = s;
        }
        {
            int row = tid >> 2, seg = tid & 3;
            short8 v = *(const short8*)&Bt[(size_t)(n0 + row) * K + k0 + seg * 8];
            *(short8*)&Bs[row * GSTR + seg * 8] = v;
        }
        __syncthreads();
        short8 af[2], bf[2];
#pragma unroll
        for (int t = 0; t < 2; t++) {
            af[t] = *(const short8*)&As[(wm * 32 + t * 16 + mm) * GSTR + quad * 8];
            bf[t] = *(const short8*)&Bs[(wn * 32 + t * 16 + mm) * GSTR + quad * 8];
        }
#pragma unroll
        for (int i = 0; i < 2; i++)
#pragma unroll
            for (int j = 0; j < 2; j++)
                acc[i][j] = __builtin_amdgcn_mfma_f32_16x16x32_bf16(af[i], bf[j], acc[i][j], 0, 0, 0);
        __syncthreads();
    }
#pragma unroll
    for (int i = 0; i < 2; i++) {
#pragma unroll
        for (int j = 0; j < 2; j++) {
            int ncol = n0 + wn * 32 + j * 16 + mm;
            float bv = bias[ncol];
#pragma unroll
            for (int r = 0; r < 4; r++) {
                int mrow = m0 + wm * 32 + i * 16 + quad * 4 + r;
                C[(size_t)mrow * Nc + ncol] = act_f<ACT>(acc[i][j][r] + bv);
            }
        }
    }
}

// ---------------- row LayerNorm + optional ELU + residual ----------------
template<int ACT>
__global__ __launch_bounds__(256) void ln_res_kernel(
        const float* __restrict__ t, const float* __restrict__ res,
        const float* __restrict__ g, const float* __restrict__ b,
        float* __restrict__ out) {
    __shared__ float red[8];
    int row = blockIdx.x, tid = threadIdx.x;
    float v = t[(size_t)row * D + tid];
    int wid = tid >> 6, lane = tid & 63;
    float s = wave_sum(v);
    if (lane == 0) red[wid] = s;
    __syncthreads();
    float mu = (red[0] + red[1] + red[2] + red[3]) * (1.f / D);
    float dv = v - mu;
    float s2 = wave_sum(dv * dv);
    if (lane == 0) red[4 + wid] = s2;
    __syncthreads();
    float var = (red[4] + red[5] + red[6] + red[7]) * (1.f / D);
    float y = dv * rsqrtf(var + 1e-5f) * g[tid] + b[tid];
    y = act_f<ACT>(y);
    out[(size_t)row * D + tid] = res[(size_t)row * D + tid] + y;
}

// ---------------- MFMA flash attention (split-K partials) ----------------
#define KSTR 40
#define VSTR 136
#define ATILE 128
__global__ __launch_bounds__(256) void attn_mfma_kernel(
        const float* __restrict__ qkv, float* __restrict__ po,
        float* __restrict__ pm, float* __restrict__ pl, int N, int KC_) {
    __shared__ __align__(16) short Ks[ATILE * KSTR];
    __shared__ __align__(16) short VTs[HD * VSTR];
    const int tid = threadIdx.x;
    const int wave = tid >> 6, lane = tid & 63;
    const int mm = lane & 15, quad = lane >> 4;
    const int h = blockIdx.y, c = blockIdx.z;
    const int qbase = blockIdx.x * 64 + wave * 16;
    const float scale = 0.17677669529663687f; // 1/sqrt(32)

    short8 qf;
    {
        const float* qrow = qkv + (size_t)(qbase + mm) * (3 * D) + h * HD + quad * 8;
        float4 a = *(const float4*)qrow;
        float4 b = *(const float4*)(qrow + 4);
        qf[0] = f2bf(a.x * scale); qf[1] = f2bf(a.y * scale);
        qf[2] = f2bf(a.z * scale); qf[3] = f2bf(a.w * scale);
        qf[4] = f2bf(b.x * scale); qf[5] = f2bf(b.y * scale);
        qf[6] = f2bf(b.z * scale); qf[7] = f2bf(b.w * scale);
    }
    floatx4 accA = {0.f, 0.f, 0.f, 0.f};
    floatx4 accB = {0.f, 0.f, 0.f, 0.f};
    float m_r = -1e30f, l_r = 0.f;

    const int kchunk = N / KC_;
    const int kstart = c * kchunk;
    const int krow0 = ((mm >> 2) << 3) | (mm & 3);

    for (int t0 = 0; t0 < kchunk; t0 += ATILE) {
#pragma unroll
        for (int p = 0; p < 4; p++) {
            int slot = tid + p * 256;
            int kr = slot >> 3, e4 = slot & 7;
            const float* krow = qkv + (size_t)(kstart + t0 + kr) * (3 * D) + D + h * HD + e4 * 4;
            float4 kv = *(const float4*)krow;
            short4v ks;
            ks[0] = f2bf(kv.x); ks[1] = f2bf(kv.y); ks[2] = f2bf(kv.z); ks[3] = f2bf(kv.w);
            *(short4v*)&Ks[kr * KSTR + e4 * 4] = ks;
            const float* vrow = qkv + (size_t)(kstart + t0 + kr) * (3 * D) + 2 * D + h * HD + e4 * 4;
            float4 vv = *(const float4*)vrow;
            VTs[(e4 * 4 + 0) * VSTR + kr] = f2bf(vv.x);
            VTs[(e4 * 4 + 1) * VSTR + kr] = f2bf(vv.y);
            VTs[(e4 * 4 + 2) * VSTR + kr] = f2bf(vv.z);
            VTs[(e4 * 4 + 3) * VSTR + kr] = f2bf(vv.w);
        }
        __syncthreads();
#pragma unroll
        for (int s = 0; s < ATILE / 32; s++) {
            int sb = s * 32;
            short8 kf0 = *(const short8*)&Ks[(sb + krow0) * KSTR + quad * 8];
            short8 kf1 = *(const short8*)&Ks[(sb + krow0 + 4) * KSTR + quad * 8];
            floatx4 zero = {0.f, 0.f, 0.f, 0.f};
            floatx4 s0 = __builtin_amdgcn_mfma_f32_16x16x32_bf16(kf0, qf, zero, 0, 0, 0);
            floatx4 s1 = __builtin_amdgcn_mfma_f32_16x16x32_bf16(kf1, qf, zero, 0, 0, 0);
            float mx = fmaxf(fmaxf(fmaxf(s0[0], s0[1]), fmaxf(s0[2], s0[3])),
                             fmaxf(fmaxf(s1[0], s1[1]), fmaxf(s1[2], s1[3])));
            mx = fmaxf(mx, __shfl_xor(mx, 16));
            mx = fmaxf(mx, __shfl_xor(mx, 32));
            float nm = fmaxf(m_r, mx);
            float alpha = __expf(m_r - nm);
            float p0[4], p1[4], ls = 0.f;
#pragma unroll
            for (int j = 0; j < 4; j++) {
                p0[j] = __expf(s0[j] - nm);
                p1[j] = __expf(s1[j] - nm);
                ls += p0[j] + p1[j];
            }
            ls += __shfl_xor(ls, 16);
            ls += __shfl_xor(ls, 32);
            l_r = l_r * alpha + ls;
            m_r = nm;
            short8 pf;
#pragma unroll
            for (int j = 0; j < 4; j++) { pf[j] = f2bf(p0[j]); pf[4 + j] = f2bf(p1[j]); }
#pragma unroll
            for (int j = 0; j < 4; j++) { accA[j] *= alpha; accB[j] *= alpha; }
            short8 vf0 = *(const short8*)&VTs[mm * VSTR + sb + quad * 8];
            short8 vf1 = *(const short8*)&VTs[(mm + 16) * VSTR + sb + quad * 8];
            accA = __builtin_amdgcn_mfma_f32_16x16x32_bf16(vf0, pf, accA, 0, 0, 0);
            accB = __builtin_amdgcn_mfma_f32_16x16x32_bf16(vf1, pf, accB, 0, 0, 0);
        }
        __syncthreads();
    }
    size_t NH = (size_t)N * H;
    int qi = qbase + mm;
    size_t nh = (size_t)qi * H + h;
    if (lane < 16) {
        pm[(size_t)c * NH + nh] = m_r;
        pl[(size_t)c * NH + nh] = l_r;
    }
    float* op = po + ((size_t)c * NH + nh) * HD;
#pragma unroll
    for (int j = 0; j < 4; j++) {
        op[quad * 4 + j] = accA[j];
        op[16 + quad * 4 + j] = accB[j];
    }
}

// ---------------- combine partials -> obuf[N, 256] ----------------
__global__ __launch_bounds__(256) void attn_combine_kernel(
        const float* __restrict__ po, const float* __restrict__ pm,
        const float* __restrict__ pl, float* __restrict__ obuf, int N, int KC_) {
    int idx = blockIdx.x * 256 + threadIdx.x;
    int d = idx & (HD - 1);
    int nh = idx >> 5;
    size_t NH = (size_t)N * H;
    float M = -1e30f;
    for (int cc = 0; cc < KC_; cc++) M = fmaxf(M, pm[(size_t)cc * NH + nh]);
    float l = 0.f, o = 0.f;
    for (int cc = 0; cc < KC_; cc++) {
        float a = __expf(pm[(size_t)cc * NH + nh] - M);
        l += a * pl[(size_t)cc * NH + nh];
        o += a * po[((size_t)cc * NH + nh) * HD + d];
    }
    int n = nh >> 3, h = nh & (H - 1);
    obuf[(size_t)n * D + h * HD + d] = o / l;
}

// ---------------- launch ----------------
extern "C" void kernel_launch(void* const* d_in, const int* in_sizes, int n_in,
                              void* d_out, int out_size, void* d_ws, size_t ws_size,
                              hipStream_t stream) {
    const float* x    = (const float*)d_in[0];
    const int*   ei   = (const int*)d_in[1];
    const float* ea   = (const float*)d_in[2];
    const float* eps  = (const float*)d_in[3];
    const float* Wl   = (const float*)d_in[4];
    const float* bl   = (const float*)d_in[5];
    const float* W1   = (const float*)d_in[6];
    const float* b1   = (const float*)d_in[7];
    const float* W2   = (const float*)d_in[8];
    const float* b2   = (const float*)d_in[9];
    const float* lnlg = (const float*)d_in[10];
    const float* lnlb = (const float*)d_in[11];
    const float* in_w = (const float*)d_in[12];
    const float* in_b = (const float*)d_in[13];
    const float* outw = (const float*)d_in[14];
    const float* outb = (const float*)d_in[15];
    const float* lnag = (const float*)d_in[16];
    const float* lnab = (const float*)d_in[17];
    const float* Wf1  = (const float*)d_in[18];
    const float* bf1  = (const float*)d_in[19];
    const float* Wf2  = (const float*)d_in[20];
    const float* bf2  = (const float*)d_in[21];
    const float* lnfg = (const float*)d_in[22];
    const float* lnfb = (const float*)d_in[23];
    float* out = (float*)d_out;

    const int N = in_sizes[0] / D;       // 4096
    const int E = in_sizes[1] / 2;       // 262144
    const size_t NF = (size_t)N * D;     // 1048576
    const size_t NH = (size_t)N * H;

    const int KCsel = 4;
    size_t floatEnd = (4 + (size_t)KCsel) * NF + 2 * (size_t)KCsel * NH;
    size_t offB = (floatEnd * 4 + 15) & ~(size_t)15;
    size_t intCount = (size_t)N + 3 * (size_t)E + (size_t)(N + 1);
    size_t wltOff = (offB + intCount * 4 + 15) & ~(size_t)15;

    float* w = (float*)d_ws;
    float* x1   = w;
    float* qkv  = w + NF;
    float* h    = w + 4 * NF;
    float* t1   = w + 5 * NF;
    float* t2   = w + 6 * NF;
    float* po   = w + 4 * NF;
    float* pm   = w + (4 + (size_t)KCsel) * NF;
    float* pl   = pm + (size_t)KCsel * NH;
    float* obuf = w + NF;
    float* t3   = w + 2 * NF;
    float* x2   = w + 3 * NF;
    float* f1   = w + 4 * NF;
    float* f2   = w + 6 * NF;

    char* base = (char*)d_ws;
    int* ibase  = (int*)(base + offB);
    int* cnt    = ibase;
    int* perm   = ibase + N;
    int* srcp   = perm + E;
    int* dstp   = srcp + E;
    int* offs   = dstp + E;
    short* WlT    = (short*)(base + wltOff);   // 16384
    short* W1bt   = WlT + 16384;               // [256][256]
    short* W2bt   = W1bt + 65536;
    short* inwbt  = W2bt + 65536;              // [768][256]
    short* outwbt = inwbt + 196608;            // [256][256]
    short* Wf1bt  = outwbt + 65536;            // [512][256]
    short* Wf2bt  = Wf1bt + 131072;            // [256][512]

    // --- weight conversions (bf16, [N][K] layout) ---
    wlT_kernel<<<64, 256, 0, stream>>>(Wl, WlT);
    convt_kernel<<<256, 256, 0, stream>>>(W1, W1bt, 256, 256);
    convt_kernel<<<256, 256, 0, stream>>>(W2, W2bt, 256, 256);
    conv_kernel<<<768, 256, 0, stream>>>(in_w, inwbt, 196608);
    conv_kernel<<<256, 256, 0, stream>>>(outw, outwbt, 65536);
    convt_kernel<<<512, 256, 0, stream>>>(Wf1, Wf1bt, 256, 512);
    convt_kernel<<<512, 256, 0, stream>>>(Wf2, Wf2bt, 512, 256);

    // --- edge binning ---
    zero_kernel<<<(N + 255) / 256, 256, 0, stream>>>(cnt, N);
    hist_kernel<<<(E + 255) / 256, 256, 0, stream>>>(ei, cnt, E);
    scan_kernel<<<1, 1024, 0, stream>>>(cnt, offs);
    scatter_kernel<<<(E + 255) / 256, 256, 0, stream>>>(ei, cnt, perm, srcp, dstp, E);
    // --- fused GINE ---
    init_h_kernel<<<(int)(NF / 256), 256, 0, stream>>>(x, eps, h, (int)NF);
    edge_fused_kernel<<<E / 64, 256, 0, stream>>>(ea, WlT, bl, x, perm, srcp, dstp, h);
    // --- local MLP ---
    gemm_bf16_kernel<2><<<dim3(D / 64, N / 64), 256, 0, stream>>>(h, W1bt, b1, t1, N, D, D);
    gemm_bf16_kernel<0><<<dim3(D / 64, N / 64), 256, 0, stream>>>(t1, W2bt, b2, t2, N, D, D);
    ln_res_kernel<2><<<N, 256, 0, stream>>>(t2, x, lnlg, lnlb, x1);
    // --- attention ---
    gemm_bf16_kernel<0><<<dim3(3 * D / 64, N / 64), 256, 0, stream>>>(x1, inwbt, in_b, qkv, N, D, 3 * D);
    attn_mfma_kernel<<<dim3(N / 64, H, KCsel), 256, 0, stream>>>(qkv, po, pm, pl, N, KCsel);
    attn_combine_kernel<<<(int)(NF / 256), 256, 0, stream>>>(po, pm, pl, obuf, N, KCsel);
    gemm_bf16_kernel<0><<<dim3(D / 64, N / 64), 256, 0, stream>>>(obuf, outwbt, outb, t3, N, D, D);
    ln_res_kernel<0><<<N, 256, 0, stream>>>(t3, x1, lnag, lnab, x2);
    // --- FFN ---
    gemm_bf16_kernel<3><<<dim3(2 * D / 64, N / 64), 256, 0, stream>>>(x2, Wf1bt, bf1, f1, N, D, 2 * D);
    gemm_bf16_kernel<0><<<dim3(D / 64, N / 64), 256, 0, stream>>>(f1, Wf2bt, bf2, f2, N, 2 * D, D);
    ln_res_kernel<0><<<N, 256, 0, stream>>>(f2, x2, lnfg, lnfb, out);

    (void)n_in; (void)out_size; (void)ws_size;
}

// Round 9
// 426.459 us; speedup vs baseline: 1.5692x; 1.0687x over previous
//
#include <hip/hip_runtime.h>
#include <cstddef>

#define D 256
#define H 8
#define HD 32
#define ED 64
#define TPB 4

typedef __attribute__((ext_vector_type(8))) short short8;
typedef __attribute__((ext_vector_type(4))) short short4v;
typedef __attribute__((ext_vector_type(4))) float floatx4;

// fp32 -> bf16 RNE
__device__ inline short f2bf(float f) {
    unsigned u = __float_as_uint(f);
    unsigned r = (u + 0x7fffu + ((u >> 16) & 1u)) >> 16;
    return (short)r;
}

// ---------------- activations ----------------
template<int ACT> __device__ inline float act_f(float v) {
    if (ACT == 1) return fmaxf(v, 0.f);
    if (ACT == 2) return v > 0.f ? v : expm1f(v);              // elu
    if (ACT == 3) return 0.5f * v * (1.f + erff(v * 0.70710678118654752f)); // exact gelu
    return v;
}

__device__ inline float wave_sum(float v) {
#pragma unroll
    for (int off = 32; off > 0; off >>= 1) v += __shfl_xor(v, off, 64);
    return v;
}

// ================= fused prep: all weight conversions + cnt zero + h init =========
__global__ void prep_kernel(
        const float* __restrict__ Wl, const float* __restrict__ W1,
        const float* __restrict__ W2, const float* __restrict__ in_w,
        const float* __restrict__ outw, const float* __restrict__ Wf1,
        const float* __restrict__ Wf2, const float* __restrict__ x,
        const float* __restrict__ eps,
        short* __restrict__ WlT, short* __restrict__ W1bt, short* __restrict__ W2bt,
        short* __restrict__ inwbt, short* __restrict__ outwbt,
        short* __restrict__ Wf1bt, short* __restrict__ Wf2bt,
        int* __restrict__ cnt, float* __restrict__ h, int N, int NF) {
    int idx = blockIdx.x * 256 + threadIdx.x;
    if (idx < 16384) { int n = idx >> 6, k = idx & 63; WlT[idx] = f2bf(Wl[k * 256 + n]); return; }
    idx -= 16384;
    if (idx < 65536) { int n = idx >> 8, k = idx & 255; W1bt[idx] = f2bf(W1[k * 256 + n]); return; }
    idx -= 65536;
    if (idx < 65536) { int n = idx >> 8, k = idx & 255; W2bt[idx] = f2bf(W2[k * 256 + n]); return; }
    idx -= 65536;
    if (idx < 196608) { inwbt[idx] = f2bf(in_w[idx]); return; }
    idx -= 196608;
    if (idx < 65536) { outwbt[idx] = f2bf(outw[idx]); return; }
    idx -= 65536;
    if (idx < 131072) { int n = idx >> 8, k = idx & 255; Wf1bt[idx] = f2bf(Wf1[k * 512 + n]); return; }
    idx -= 131072;
    if (idx < 131072) { int n = idx >> 9, k = idx & 511; Wf2bt[idx] = f2bf(Wf2[k * 256 + n]); return; }
    idx -= 131072;
    if (idx < N) { cnt[idx] = 0; return; }
    idx -= N;
    if (idx < NF) { h[idx] = (1.f + eps[0]) * x[idx]; }
}

// ================= edge binning =================
__global__ void hist_kernel(const int* __restrict__ ei, int* __restrict__ cnt, int E) {
    int e = blockIdx.x * 256 + threadIdx.x;
    if (e < E) atomicAdd(&cnt[ei[E + e]], 1);
}

__global__ __launch_bounds__(1024) void scan_kernel(int* __restrict__ cnt,
                                                    int* __restrict__ offs) {
    __shared__ int s[1024];
    int tid = threadIdx.x;
    int4 c = *(int4*)&cnt[tid * 4];
    int sum = c.x + c.y + c.z + c.w;
    s[tid] = sum;
    __syncthreads();
    for (int off = 1; off < 1024; off <<= 1) {
        int v = (tid >= off) ? s[tid - off] : 0;
        __syncthreads();
        s[tid] += v;
        __syncthreads();
    }
    int ex = s[tid] - sum;
    int o1 = ex + c.x, o2 = o1 + c.y, o3 = o2 + c.z;
    offs[tid * 4] = ex; offs[tid * 4 + 1] = o1;
    offs[tid * 4 + 2] = o2; offs[tid * 4 + 3] = o3;
    cnt[tid * 4] = ex; cnt[tid * 4 + 1] = o1;
    cnt[tid * 4 + 2] = o2; cnt[tid * 4 + 3] = o3;
    if (tid == 1023) offs[4096] = s[1023];
}

__global__ void scatter_kernel(const int* __restrict__ ei, int* __restrict__ cursor,
                               int* __restrict__ perm, int* __restrict__ srcp,
                               int* __restrict__ dstp, int E) {
    int e = blockIdx.x * 256 + threadIdx.x;
    if (e < E) {
        int d = ei[E + e];
        int pos = atomicAdd(&cursor[d], 1);
        perm[pos] = e;
        srcp[pos] = ei[e];
        dstp[pos] = d;
    }
}

// Fused GINE edge kernel: 4 tiles of 64 edges per block, double-buffered LDS
// staging so ea gathers for tile t+1 are in flight during tile t's compute.
__global__ __launch_bounds__(256) void edge_fused_kernel(
        const float* __restrict__ ea, const short* __restrict__ WlT,
        const float* __restrict__ bl, const float* __restrict__ x,
        const int* __restrict__ perm, const int* __restrict__ srcp,
        const int* __restrict__ dstp, float* __restrict__ h) {
    __shared__ __align__(16) short ea_s[2][64 * 72];
    int tid = threadIdx.x;
    int wave = tid >> 6, lane = tid & 63;
    int mm = lane & 15, quad = lane >> 4;
    int base_e = blockIdx.x * (64 * TPB);

    // metadata for all tiles, registers (coalesced loads, all in flight)
    int myperm[TPB], mysrc[TPB], mydst[TPB];
#pragma unroll
    for (int t = 0; t < TPB; t++) {
        myperm[t] = perm[base_e + t * 64 + lane];
        mysrc[t]  = srcp[base_e + t * 64 + lane];
        mydst[t]  = dstp[base_e + t * 64 + lane];
    }
    // A fragments + bias (loop-invariant)
    short8 af[4][2];
#pragma unroll
    for (int t = 0; t < 4; t++)
#pragma unroll
        for (int q2 = 0; q2 < 2; q2++)
            af[t][q2] = *(const short8*)&WlT[(wave * 64 + t * 16 + mm) * 64 + q2 * 32 + quad * 8];
    float4 blv[4];
#pragma unroll
    for (int t = 0; t < 4; t++)
        blv[t] = *(const float4*)&bl[wave * 64 + t * 16 + quad * 4];

    // stage tile 0 into buf 0
    {
        float4 r[4];
#pragma unroll
        for (int p = 0; p < 4; p++) {
            int slot = tid + p * 256;
            int row = slot >> 4, c4 = slot & 15;
            int prow = __shfl(myperm[0], row);
            r[p] = *(const float4*)&ea[(size_t)prow * ED + c4 * 4];
        }
#pragma unroll
        for (int p = 0; p < 4; p++) {
            int slot = tid + p * 256;
            int row = slot >> 4, c4 = slot & 15;
            short4v s; s[0] = f2bf(r[p].x); s[1] = f2bf(r[p].y); s[2] = f2bf(r[p].z); s[3] = f2bf(r[p].w);
            *(short4v*)&ea_s[0][row * 72 + c4 * 4] = s;
        }
    }
    __syncthreads();

#pragma unroll
    for (int t = 0; t < TPB; t++) {
        const int buf = t & 1;
        // issue prefetch for tile t+1 (loads in flight across compute below)
        float4 pre[4];
        if (t + 1 < TPB) {
#pragma unroll
            for (int p = 0; p < 4; p++) {
                int slot = tid + p * 256;
                int row = slot >> 4, c4 = slot & 15;
                int prow = __shfl(myperm[t + 1], row);
                pre[p] = *(const float4*)&ea[(size_t)prow * ED + c4 * 4];
            }
        }
        // MFMA edge-linear for tile t
        floatx4 acc[4][4];
#pragma unroll
        for (int et = 0; et < 4; et++)
#pragma unroll
            for (int tt = 0; tt < 4; tt++) acc[et][tt] = (floatx4){0.f, 0.f, 0.f, 0.f};
#pragma unroll
        for (int et = 0; et < 4; et++) {
            short8 bf0 = *(const short8*)&ea_s[buf][(et * 16 + mm) * 72 + quad * 8];
            short8 bf1 = *(const short8*)&ea_s[buf][(et * 16 + mm) * 72 + 32 + quad * 8];
#pragma unroll
            for (int tt = 0; tt < 4; tt++) {
                acc[et][tt] = __builtin_amdgcn_mfma_f32_16x16x32_bf16(af[tt][0], bf0, acc[et][tt], 0, 0, 0);
                acc[et][tt] = __builtin_amdgcn_mfma_f32_16x16x32_bf16(af[tt][1], bf1, acc[et][tt], 0, 0, 0);
            }
        }
        // + bias + x[src] gather + relu
#pragma unroll
        for (int et = 0; et < 4; et++) {
            int srci = __shfl(mysrc[t], et * 16 + mm);
            const float* xrow = x + (size_t)srci * D + wave * 64 + quad * 4;
#pragma unroll
            for (int tt = 0; tt < 4; tt++) {
                float4 xv = *(const float4*)(xrow + tt * 16);
                acc[et][tt][0] = fmaxf(acc[et][tt][0] + blv[tt].x + xv.x, 0.f);
                acc[et][tt][1] = fmaxf(acc[et][tt][1] + blv[tt].y + xv.y, 0.f);
                acc[et][tt][2] = fmaxf(acc[et][tt][2] + blv[tt].z + xv.z, 0.f);
                acc[et][tt][3] = fmaxf(acc[et][tt][3] + blv[tt].w + xv.w, 0.f);
            }
        }
        // ballot-based segmentation over mydst[t]
        int prevd = __shfl_up(mydst[t], 1);
        bool bnd = (lane == 0) || (mydst[t] != prevd);
        unsigned long long m = __ballot(bnd);
        while (m) {
            int segstart = (int)__builtin_ctzll(m);
            m &= m - 1;
            int segend = m ? (int)__builtin_ctzll(m) : 64;
            int segdst = __shfl(mydst[t], segstart);
            bool in0 = (0 * 16 + mm >= segstart) & (0 * 16 + mm < segend);
            bool in1 = (1 * 16 + mm >= segstart) & (1 * 16 + mm < segend);
            bool in2 = (2 * 16 + mm >= segstart) & (2 * 16 + mm < segend);
            bool in3 = (3 * 16 + mm >= segstart) & (3 * 16 + mm < segend);
            float* hrow = h + (size_t)segdst * D + wave * 64;
#pragma unroll
            for (int tt = 0; tt < 4; tt++) {
#pragma unroll
                for (int j = 0; j < 4; j++) {
                    float v = (in0 ? acc[0][tt][j] : 0.f) + (in1 ? acc[1][tt][j] : 0.f)
                            + (in2 ? acc[2][tt][j] : 0.f) + (in3 ? acc[3][tt][j] : 0.f);
                    v += __shfl_xor(v, 1);
                    v += __shfl_xor(v, 2);
                    v += __shfl_xor(v, 4);
                    v += __shfl_xor(v, 8);
                    if (mm == 0) atomicAdd(&hrow[tt * 16 + quad * 4 + j], v);
                }
            }
        }
        // write prefetched tile into the other buffer
        if (t + 1 < TPB) {
#pragma unroll
            for (int p = 0; p < 4; p++) {
                int slot = tid + p * 256;
                int row = slot >> 4, c4 = slot & 15;
                short4v s; s[0] = f2bf(pre[p].x); s[1] = f2bf(pre[p].y);
                s[2] = f2bf(pre[p].z); s[3] = f2bf(pre[p].w);
                *(short4v*)&ea_s[1 - buf][row * 72 + c4 * 4] = s;
            }
            __syncthreads();
        }
    }
}

// ---------------- bf16 MFMA GEMM: C[M,Nc] = act(A[M,K] @ Bt^T + bias) ----------------
#define GSTR 40
template<int ACT>
__global__ __launch_bounds__(256) void gemm_bf16_kernel(
        const float* __restrict__ A, const short* __restrict__ Bt,
        const float* __restrict__ bias, float* __restrict__ C,
        int M, int K, int Nc) {
    __shared__ __align__(16) short As[64 * GSTR];
    __shared__ __align__(16) short Bs[64 * GSTR];
    int tid = threadIdx.x;
    int wave = tid >> 6, lane = tid & 63;
    int mm = lane & 15, quad = lane >> 4;
    int wm = wave >> 1, wn = wave & 1;
    int m0 = blockIdx.y * 64, n0 = blockIdx.x * 64;
    floatx4 acc[2][2];
#pragma unroll
    for (int i = 0; i < 2; i++)
#pragma unroll
        for (int j = 0; j < 2; j++) acc[i][j] = (floatx4){0.f, 0.f, 0.f, 0.f};
    for (int k0 = 0; k0 < K; k0 += 32) {
#pragma unroll
        for (int p = 0; p < 2; p++) {
            int slot = tid + p * 256;
            int row = slot >> 3, c4 = slot & 7;
            float4 v = *(const float4*)&A[(size_t)(m0 + row) * K + k0 + c4 * 4];
            short4v s; s[0] = f2bf(v.x); s[1] = f2bf(v.y); s[2] = f2bf(v.z); s[3] = f2bf(v.w);
            *(short4v*)&As[row * GSTR + c4 * 4] = s;
        }
        {
            int row = tid >> 2, seg = tid & 3;
            short8 v = *(const short8*)&Bt[(size_t)(n0 + row) * K + k0 + seg * 8];
            *(short8*)&Bs[row * GSTR + seg * 8] = v;
        }
        __syncthreads();
        short8 af[2], bf[2];
#pragma unroll
        for (int t = 0; t < 2; t++) {
            af[t] = *(const short8*)&As[(wm * 32 + t * 16 + mm) * GSTR + quad * 8];
            bf[t] = *(const short8*)&Bs[(wn * 32 + t * 16 + mm) * GSTR + quad * 8];
        }
#pragma unroll
        for (int i = 0; i < 2; i++)
#pragma unroll
            for (int j = 0; j < 2; j++)
                acc[i][j] = __builtin_amdgcn_mfma_f32_16x16x32_bf16(af[i], bf[j], acc[i][j], 0, 0, 0);
        __syncthreads();
    }
#pragma unroll
    for (int i = 0; i < 2; i++) {
#pragma unroll
        for (int j = 0; j < 2; j++) {
            int ncol = n0 + wn * 32 + j * 16 + mm;
            float bv = bias[ncol];
#pragma unroll
            for (int r = 0; r < 4; r++) {
                int mrow = m0 + wm * 32 + i * 16 + quad * 4 + r;
                C[(size_t)mrow * Nc + ncol] = act_f<ACT>(acc[i][j][r] + bv);
            }
        }
    }
}

// ---------------- row LayerNorm + optional ELU + residual ----------------
template<int ACT>
__global__ __launch_bounds__(256) void ln_res_kernel(
        const float* __restrict__ t, const float* __restrict__ res,
        const float* __restrict__ g, const float* __restrict__ b,
        float* __restrict__ out) {
    __shared__ float red[8];
    int row = blockIdx.x, tid = threadIdx.x;
    float v = t[(size_t)row * D + tid];
    int wid = tid >> 6, lane = tid & 63;
    float s = wave_sum(v);
    if (lane == 0) red[wid] = s;
    __syncthreads();
    float mu = (red[0] + red[1] + red[2] + red[3]) * (1.f / D);
    float dv = v - mu;
    float s2 = wave_sum(dv * dv);
    if (lane == 0) red[4 + wid] = s2;
    __syncthreads();
    float var = (red[4] + red[5] + red[6] + red[7]) * (1.f / D);
    float y = dv * rsqrtf(var + 1e-5f) * g[tid] + b[tid];
    y = act_f<ACT>(y);
    out[(size_t)row * D + tid] = res[(size_t)row * D + tid] + y;
}

// ---------------- MFMA flash attention (split-K partials) ----------------
#define KSTR 40
#define VSTR 136
#define ATILE 128
__global__ __launch_bounds__(256) void attn_mfma_kernel(
        const float* __restrict__ qkv, float* __restrict__ po,
        float* __restrict__ pm, float* __restrict__ pl, int N, int KC_) {
    __shared__ __align__(16) short Ks[ATILE * KSTR];
    __shared__ __align__(16) short VTs[HD * VSTR];
    const int tid = threadIdx.x;
    const int wave = tid >> 6, lane = tid & 63;
    const int mm = lane & 15, quad = lane >> 4;
    const int h = blockIdx.y, c = blockIdx.z;
    const int qbase = blockIdx.x * 64 + wave * 16;
    const float scale = 0.17677669529663687f; // 1/sqrt(32)

    short8 qf;
    {
        const float* qrow = qkv + (size_t)(qbase + mm) * (3 * D) + h * HD + quad * 8;
        float4 a = *(const float4*)qrow;
        float4 b = *(const float4*)(qrow + 4);
        qf[0] = f2bf(a.x * scale); qf[1] = f2bf(a.y * scale);
        qf[2] = f2bf(a.z * scale); qf[3] = f2bf(a.w * scale);
        qf[4] = f2bf(b.x * scale); qf[5] = f2bf(b.y * scale);
        qf[6] = f2bf(b.z * scale); qf[7] = f2bf(b.w * scale);
    }
    floatx4 accA = {0.f, 0.f, 0.f, 0.f};
    floatx4 accB = {0.f, 0.f, 0.f, 0.f};
    float m_r = -1e30f, l_r = 0.f;

    const int kchunk = N / KC_;
    const int kstart = c * kchunk;
    const int krow0 = ((mm >> 2) << 3) | (mm & 3);

    for (int t0 = 0; t0 < kchunk; t0 += ATILE) {
#pragma unroll
        for (int p = 0; p < 4; p++) {
            int slot = tid + p * 256;
            int kr = slot >> 3, e4 = slot & 7;
            const float* krow = qkv + (size_t)(kstart + t0 + kr) * (3 * D) + D + h * HD + e4 * 4;
            float4 kv = *(const float4*)krow;
            short4v ks;
            ks[0] = f2bf(kv.x); ks[1] = f2bf(kv.y); ks[2] = f2bf(kv.z); ks[3] = f2bf(kv.w);
            *(short4v*)&Ks[kr * KSTR + e4 * 4] = ks;
            const float* vrow = qkv + (size_t)(kstart + t0 + kr) * (3 * D) + 2 * D + h * HD + e4 * 4;
            float4 vv = *(const float4*)vrow;
            VTs[(e4 * 4 + 0) * VSTR + kr] = f2bf(vv.x);
            VTs[(e4 * 4 + 1) * VSTR + kr] = f2bf(vv.y);
            VTs[(e4 * 4 + 2) * VSTR + kr] = f2bf(vv.z);
            VTs[(e4 * 4 + 3) * VSTR + kr] = f2bf(vv.w);
        }
        __syncthreads();
#pragma unroll
        for (int s = 0; s < ATILE / 32; s++) {
            int sb = s * 32;
            short8 kf0 = *(const short8*)&Ks[(sb + krow0) * KSTR + quad * 8];
            short8 kf1 = *(const short8*)&Ks[(sb + krow0 + 4) * KSTR + quad * 8];
            floatx4 zero = {0.f, 0.f, 0.f, 0.f};
            floatx4 s0 = __builtin_amdgcn_mfma_f32_16x16x32_bf16(kf0, qf, zero, 0, 0, 0);
            floatx4 s1 = __builtin_amdgcn_mfma_f32_16x16x32_bf16(kf1, qf, zero, 0, 0, 0);
            float mx = fmaxf(fmaxf(fmaxf(s0[0], s0[1]), fmaxf(s0[2], s0[3])),
                             fmaxf(fmaxf(s1[0], s1[1]), fmaxf(s1[2], s1[3])));
            mx = fmaxf(mx, __shfl_xor(mx, 16));
            mx = fmaxf(mx, __shfl_xor(mx, 32));
            float nm = fmaxf(m_r, mx);
            float alpha = __expf(m_r - nm);
            float p0[4], p1[4], ls = 0.f;
#pragma unroll
            for (int j = 0; j < 4; j++) {
                p0[j] = __expf(s0[j] - nm);
                p1[j] = __expf(s1[j] - nm);
                ls += p0[j] + p1[j];
            }
            ls += __shfl_xor(ls, 16);
            ls += __shfl_xor(ls, 32);
            l_r = l_r * alpha + ls;
            m_r = nm;
            short8 pf;
#pragma unroll
            for (int j = 0; j < 4; j++) { pf[j] = f2bf(p0[j]); pf[4 + j] = f2bf(p1[j]); }
#pragma unroll
            for (int j = 0; j < 4; j++) { accA[j] *= alpha; accB[j] *= alpha; }
            short8 vf0 = *(const short8*)&VTs[mm * VSTR + sb + quad * 8];
            short8 vf1 = *(const short8*)&VTs[(mm + 16) * VSTR + sb + quad * 8];
            accA = __builtin_amdgcn_mfma_f32_16x16x32_bf16(vf0, pf, accA, 0, 0, 0);
            accB = __builtin_amdgcn_mfma_f32_16x16x32_bf16(vf1, pf, accB, 0, 0, 0);
        }
        __syncthreads();
    }
    size_t NH = (size_t)N * H;
    int qi = qbase + mm;
    size_t nh = (size_t)qi * H + h;
    if (lane < 16) {
        pm[(size_t)c * NH + nh] = m_r;
        pl[(size_t)c * NH + nh] = l_r;
    }
    float* op = po + ((size_t)c * NH + nh) * HD;
#pragma unroll
    for (int j = 0; j < 4; j++) {
        op[quad * 4 + j] = accA[j];
        op[16 + quad * 4 + j] = accB[j];
    }
}

// ---------------- combine partials -> obuf[N, 256] ----------------
__global__ __launch_bounds__(256) void attn_combine_kernel(
        const float* __restrict__ po, const float* __restrict__ pm,
        const float* __restrict__ pl, float* __restrict__ obuf, int N, int KC_) {
    int idx = blockIdx.x * 256 + threadIdx.x;
    int d = idx & (HD - 1);
    int nh = idx >> 5;
    size_t NH = (size_t)N * H;
    float M = -1e30f;
    for (int cc = 0; cc < KC_; cc++) M = fmaxf(M, pm[(size_t)cc * NH + nh]);
    float l = 0.f, o = 0.f;
    for (int cc = 0; cc < KC_; cc++) {
        float a = __expf(pm[(size_t)cc * NH + nh] - M);
        l += a * pl[(size_t)cc * NH + nh];
        o += a * po[((size_t)cc * NH + nh) * HD + d];
    }
    int n = nh >> 3, h = nh & (H - 1);
    obuf[(size_t)n * D + h * HD + d] = o / l;
}

// ---------------- launch ----------------
extern "C" void kernel_launch(void* const* d_in, const int* in_sizes, int n_in,
                              void* d_out, int out_size, void* d_ws, size_t ws_size,
                              hipStream_t stream) {
    const float* x    = (const float*)d_in[0];
    const int*   ei   = (const int*)d_in[1];
    const float* ea   = (const float*)d_in[2];
    const float* eps  = (const float*)d_in[3];
    const float* Wl   = (const float*)d_in[4];
    const float* bl   = (const float*)d_in[5];
    const float* W1   = (const float*)d_in[6];
    const float* b1   = (const float*)d_in[7];
    const float* W2   = (const float*)d_in[8];
    const float* b2   = (const float*)d_in[9];
    const float* lnlg = (const float*)d_in[10];
    const float* lnlb = (const float*)d_in[11];
    const float* in_w = (const float*)d_in[12];
    const float* in_b = (const float*)d_in[13];
    const float* outw = (const float*)d_in[14];
    const float* outb = (const float*)d_in[15];
    const float* lnag = (const float*)d_in[16];
    const float* lnab = (const float*)d_in[17];
    const float* Wf1  = (const float*)d_in[18];
    const float* bf1  = (const float*)d_in[19];
    const float* Wf2  = (const float*)d_in[20];
    const float* bf2  = (const float*)d_in[21];
    const float* lnfg = (const float*)d_in[22];
    const float* lnfb = (const float*)d_in[23];
    float* out = (float*)d_out;

    const int N = in_sizes[0] / D;       // 4096
    const int E = in_sizes[1] / 2;       // 262144
    const size_t NF = (size_t)N * D;     // 1048576
    const size_t NH = (size_t)N * H;

    const int KCsel = 4;
    size_t floatEnd = (4 + (size_t)KCsel) * NF + 2 * (size_t)KCsel * NH;
    size_t offB = (floatEnd * 4 + 15) & ~(size_t)15;
    size_t intCount = (size_t)N + 3 * (size_t)E + (size_t)(N + 1);
    size_t wltOff = (offB + intCount * 4 + 15) & ~(size_t)15;

    float* w = (float*)d_ws;
    float* x1   = w;
    float* qkv  = w + NF;
    float* h    = w + 4 * NF;
    float* t1   = w + 5 * NF;
    float* t2   = w + 6 * NF;
    float* po   = w + 4 * NF;
    float* pm   = w + (4 + (size_t)KCsel) * NF;
    float* pl   = pm + (size_t)KCsel * NH;
    float* obuf = w + NF;
    float* t3   = w + 2 * NF;
    float* x2   = w + 3 * NF;
    float* f1   = w + 4 * NF;
    float* f2   = w + 6 * NF;

    char* base = (char*)d_ws;
    int* ibase  = (int*)(base + offB);
    int* cnt    = ibase;
    int* perm   = ibase + N;
    int* srcp   = perm + E;
    int* dstp   = srcp + E;
    int* offs   = dstp + E;
    short* WlT    = (short*)(base + wltOff);   // 16384
    short* W1bt   = WlT + 16384;               // [256][256]
    short* W2bt   = W1bt + 65536;
    short* inwbt  = W2bt + 65536;              // [768][256]
    short* outwbt = inwbt + 196608;            // [256][256]
    short* Wf1bt  = outwbt + 65536;            // [512][256]
    short* Wf2bt  = Wf1bt + 131072;            // [256][512]

    // --- fused prep: conversions + cnt zero + h init ---
    {
        int total = 671744 + N + (int)NF;
        prep_kernel<<<(total + 255) / 256, 256, 0, stream>>>(
            Wl, W1, W2, in_w, outw, Wf1, Wf2, x, eps,
            WlT, W1bt, W2bt, inwbt, outwbt, Wf1bt, Wf2bt, cnt, h, N, (int)NF);
    }
    // --- edge binning ---
    hist_kernel<<<(E + 255) / 256, 256, 0, stream>>>(ei, cnt, E);
    scan_kernel<<<1, 1024, 0, stream>>>(cnt, offs);
    scatter_kernel<<<(E + 255) / 256, 256, 0, stream>>>(ei, cnt, perm, srcp, dstp, E);
    // --- fused GINE (pipelined, 4 tiles/block) ---
    edge_fused_kernel<<<E / (64 * TPB), 256, 0, stream>>>(ea, WlT, bl, x, perm, srcp, dstp, h);
    // --- local MLP ---
    gemm_bf16_kernel<2><<<dim3(D / 64, N / 64), 256, 0, stream>>>(h, W1bt, b1, t1, N, D, D);
    gemm_bf16_kernel<0><<<dim3(D / 64, N / 64), 256, 0, stream>>>(t1, W2bt, b2, t2, N, D, D);
    ln_res_kernel<2><<<N, 256, 0, stream>>>(t2, x, lnlg, lnlb, x1);
    // --- attention ---
    gemm_bf16_kernel<0><<<dim3(3 * D / 64, N / 64), 256, 0, stream>>>(x1, inwbt, in_b, qkv, N, D, 3 * D);
    attn_mfma_kernel<<<dim3(N / 64, H, KCsel), 256, 0, stream>>>(qkv, po, pm, pl, N, KCsel);
    attn_combine_kernel<<<(int)(NF / 256), 256, 0, stream>>>(po, pm, pl, obuf, N, KCsel);
    gemm_bf16_kernel<0><<<dim3(D / 64, N / 64), 256, 0, stream>>>(obuf, outwbt, outb, t3, N, D, D);
    ln_res_kernel<0><<<N, 256, 0, stream>>>(t3, x1, lnag, lnab, x2);
    // --- FFN ---
    gemm_bf16_kernel<3><<<dim3(2 * D / 64, N / 64), 256, 0, stream>>>(x2, Wf1bt, bf1, f1, N, D, 2 * D);
    gemm_bf16_kernel<0><<<dim3(D / 64, N / 64), 256, 0, stream>>>(f1, Wf2bt, bf2, f2, N, 2 * D, D);
    ln_res_kernel<0><<<N, 256, 0, stream>>>(f2, x2, lnfg, lnfb, out);

    (void)n_in; (void)out_size; (void)ws_size;
}